// Round 2
// baseline (443.228 us; speedup 1.0000x reference)
//
#include <hip/hip_runtime.h>
#include <hip/hip_bf16.h>

#define NN   30000
#define EE   960000
#define IND  2048
#define NEMB 64
#define NH1  32
#define NH2  16
#define NET  64
#define NB   16

typedef __bf16 bf8 __attribute__((ext_vector_type(8)));
typedef float  f4  __attribute__((ext_vector_type(4)));

__device__ __forceinline__ bf8 bf8_zero() {
    bf8 z;
#pragma unroll
    for (int i = 0; i < 8; i++) z[i] = (__bf16)0.0f;
    return z;
}

// ---------------- merged prep: embT + W1T + W2T + zero(deg) ----------------
__global__ __launch_bounds__(256) void k_prep(const float* __restrict__ embed,
                                              const float* __restrict__ basis1,
                                              const float* __restrict__ att1,
                                              const float* __restrict__ basis2,
                                              const float* __restrict__ att2,
                                              __bf16* __restrict__ embT,
                                              __bf16* __restrict__ W1T,
                                              __bf16* __restrict__ W2T,
                                              int* __restrict__ deg) {
    int b = blockIdx.x;
    if (b < 512) {
        // embed [2048][64] f32 -> embT [64][2048] bf16
        int idx = b * 256 + threadIdx.x;
        int n = idx >> 11, k = idx & 2047;
        embT[idx] = (__bf16)embed[k * NEMB + n];
    } else if (b < 576) {
        int r = b - 512;
        __shared__ float a[NB];
        if (threadIdx.x < NB) a[threadIdx.x] = att1[r * NB + threadIdx.x];
        __syncthreads();
        for (int idx = threadIdx.x; idx < NH1 * NEMB; idx += 256) {
            int o = idx >> 6, i = idx & 63;
            float acc = 0.f;
#pragma unroll
            for (int bb = 0; bb < NB; bb++) acc += a[bb] * basis1[(bb * NEMB + i) * NH1 + o];
            W1T[r * (NH1 * NEMB) + idx] = (__bf16)acc;
        }
    } else if (b < 640) {
        int r = b - 576;
        __shared__ float a[NB];
        if (threadIdx.x < NB) a[threadIdx.x] = att2[r * NB + threadIdx.x];
        __syncthreads();
        for (int idx = threadIdx.x; idx < NH2 * NH1; idx += 256) {
            int o = idx >> 5, i = idx & 31;
            float acc = 0.f;
#pragma unroll
            for (int bb = 0; bb < NB; bb++) acc += a[bb] * basis2[(bb * NH1 + i) * NH2 + o];
            W2T[r * (NH2 * NH1) + idx] = (__bf16)acc;
        }
    } else {
        for (int i = (b - 640) * 256 + threadIdx.x; i < NN; i += 4 * 256) deg[i] = 0;
    }
}

// ---------------- embed GEMM: h0 = (x @ embed)/x_norm -> bf16 ----------------
__global__ __launch_bounds__(256) void k_embed(const float* __restrict__ x,
                                               const float* __restrict__ xnorm,
                                               const __bf16* __restrict__ embT,
                                               __bf16* __restrict__ h0b) {
    int lane = threadIdx.x & 63;
    int wave = threadIdx.x >> 6;
    int rowbase = blockIdx.x * 64 + wave * 16;
    int l15 = lane & 15, kg = lane >> 4;
    int arow = rowbase + l15;
    int arow_c = arow < NN ? arow : NN - 1;
    const float*  xp = x + (size_t)arow_c * IND + kg * 8;
    const __bf16* bp = embT + (size_t)l15 * IND + kg * 8;
    f4 acc0 = (f4)0.0f, acc1 = (f4)0.0f, acc2 = (f4)0.0f, acc3 = (f4)0.0f;
#pragma unroll 2
    for (int k0 = 0; k0 < IND; k0 += 32) {
        float4 lo = *(const float4*)(xp + k0);
        float4 hi = *(const float4*)(xp + k0 + 4);
        bf8 av;
        av[0] = (__bf16)lo.x; av[1] = (__bf16)lo.y; av[2] = (__bf16)lo.z; av[3] = (__bf16)lo.w;
        av[4] = (__bf16)hi.x; av[5] = (__bf16)hi.y; av[6] = (__bf16)hi.z; av[7] = (__bf16)hi.w;
        bf8 b0 = *(const bf8*)(bp + k0);
        bf8 b1 = *(const bf8*)(bp + 16 * IND + k0);
        bf8 b2 = *(const bf8*)(bp + 32 * IND + k0);
        bf8 b3 = *(const bf8*)(bp + 48 * IND + k0);
        acc0 = __builtin_amdgcn_mfma_f32_16x16x32_bf16(av, b0, acc0, 0, 0, 0);
        acc1 = __builtin_amdgcn_mfma_f32_16x16x32_bf16(av, b1, acc1, 0, 0, 0);
        acc2 = __builtin_amdgcn_mfma_f32_16x16x32_bf16(av, b2, acc2, 0, 0, 0);
        acc3 = __builtin_amdgcn_mfma_f32_16x16x32_bf16(av, b3, acc3, 0, 0, 0);
    }
#pragma unroll
    for (int j = 0; j < 4; j++) {
        int r = rowbase + kg * 4 + j;
        if (r < NN) {
            float inv = 1.0f / xnorm[r];
            __bf16* hp = h0b + (size_t)r * NEMB + l15;
            hp[0]  = (__bf16)(acc0[j] * inv);
            hp[16] = (__bf16)(acc1[j] * inv);
            hp[32] = (__bf16)(acc2[j] * inv);
            hp[48] = (__bf16)(acc3[j] * inv);
        }
    }
}

// ---------------- CSR build (by dst) ----------------
__global__ __launch_bounds__(256) void k_hist(const int* __restrict__ ei, int* __restrict__ deg) {
    int e = blockIdx.x * 256 + threadIdx.x;
    atomicAdd(&deg[ei[EE + e]], 1);
}

__global__ __launch_bounds__(1024) void k_scan(const int* __restrict__ deg,
                                               int* __restrict__ row_start,
                                               int* __restrict__ cursor) {
    __shared__ int lds[1024];
    __shared__ int base;
    int t = threadIdx.x;
    if (t == 0) base = 0;
    __syncthreads();
    for (int c0 = 0; c0 < NN; c0 += 1024) {
        int i = c0 + t;
        int v = (i < NN) ? deg[i] : 0;
        lds[t] = v;
        __syncthreads();
        for (int off = 1; off < 1024; off <<= 1) {
            int add = (t >= off) ? lds[t - off] : 0;
            __syncthreads();
            lds[t] += add;
            __syncthreads();
        }
        int excl = lds[t] - v;
        int tot = lds[1023];
        if (i < NN) { row_start[i] = base + excl; cursor[i] = base + excl; }
        __syncthreads();
        if (t == 0) base += tot;
        __syncthreads();
    }
    if (t == 0) row_start[NN] = base;
}

__global__ __launch_bounds__(256) void k_scatter(const int* __restrict__ ei,
                                                 int* __restrict__ cursor,
                                                 int* __restrict__ eperm) {
    int e = blockIdx.x * 256 + threadIdx.x;
    int dst = ei[EE + e];
    int pos = atomicAdd(&cursor[dst], 1);
    eperm[pos] = e;
}

// ---------------- edge message kernels (et-sorted 16-edge MFMA batches) ----------------
__global__ __launch_bounds__(256) void k_edge1m(const int* __restrict__ ei,
                                                const int* __restrict__ et,
                                                const __bf16* __restrict__ h0b,
                                                const __bf16* __restrict__ W1T,
                                                __bf16* __restrict__ msg1) {
    int wid = blockIdx.x * 4 + (threadIdx.x >> 6);
    int lane = threadIdx.x & 63;
    int l15 = lane & 15, kg = lane >> 4;
    int er = wid * 16 + l15;
    int my_et  = et[er];
    int my_src = ei[er];
    const __bf16* hp = h0b + (size_t)my_src * NEMB + kg * 8;
    bf8 a0 = *(const bf8*)hp;
    bf8 a1 = *(const bf8*)(hp + 32);
    bf8 zero = bf8_zero();
    f4 c0 = (f4)0.0f, c1 = (f4)0.0f;
    int pos = 0;
    while (pos < 16) {
        int r = __shfl(my_et, pos);
        unsigned long long bl = __ballot(my_et == r);
        unsigned m16 = (unsigned)(bl & 0xFFFFull);
        int run = __builtin_ctz(~(m16 >> pos));
        int end = pos + run;
        const __bf16* wb = W1T + (size_t)r * (NH1 * NEMB) + (size_t)l15 * NEMB + kg * 8;
        bf8 b00 = *(const bf8*)(wb);
        bf8 b01 = *(const bf8*)(wb + 32);
        bf8 b10 = *(const bf8*)(wb + 16 * NEMB);
        bf8 b11 = *(const bf8*)(wb + 16 * NEMB + 32);
        bool use = (l15 >= pos) && (l15 < end);
        bf8 ua0 = use ? a0 : zero;
        bf8 ua1 = use ? a1 : zero;
        c0 = __builtin_amdgcn_mfma_f32_16x16x32_bf16(ua0, b00, c0, 0, 0, 0);
        c0 = __builtin_amdgcn_mfma_f32_16x16x32_bf16(ua1, b01, c0, 0, 0, 0);
        c1 = __builtin_amdgcn_mfma_f32_16x16x32_bf16(ua0, b10, c1, 0, 0, 0);
        c1 = __builtin_amdgcn_mfma_f32_16x16x32_bf16(ua1, b11, c1, 0, 0, 0);
        pos = end;
    }
#pragma unroll
    for (int j = 0; j < 4; j++) {
        int ej = wid * 16 + kg * 4 + j;          // C row = edge index in batch
        __bf16* mp = msg1 + (size_t)ej * NH1;
        mp[l15]      = (__bf16)c0[j];
        mp[16 + l15] = (__bf16)c1[j];
    }
}

__global__ __launch_bounds__(256) void k_edge2m(const int* __restrict__ ei,
                                                const int* __restrict__ et,
                                                const __bf16* __restrict__ h1b,
                                                const __bf16* __restrict__ W2T,
                                                __bf16* __restrict__ msg2) {
    int wid = blockIdx.x * 4 + (threadIdx.x >> 6);
    int lane = threadIdx.x & 63;
    int l15 = lane & 15, kg = lane >> 4;
    int er = wid * 16 + l15;
    int my_et  = et[er];
    int my_src = ei[er];
    bf8 a = *(const bf8*)(h1b + (size_t)my_src * NH1 + kg * 8);
    bf8 zero = bf8_zero();
    f4 c = (f4)0.0f;
    int pos = 0;
    while (pos < 16) {
        int r = __shfl(my_et, pos);
        unsigned long long bl = __ballot(my_et == r);
        unsigned m16 = (unsigned)(bl & 0xFFFFull);
        int run = __builtin_ctz(~(m16 >> pos));
        int end = pos + run;
        bf8 b = *(const bf8*)(W2T + (size_t)r * (NH2 * NH1) + (size_t)l15 * NH1 + kg * 8);
        bool use = (l15 >= pos) && (l15 < end);
        c = __builtin_amdgcn_mfma_f32_16x16x32_bf16(use ? a : zero, b, c, 0, 0, 0);
        pos = end;
    }
#pragma unroll
    for (int j = 0; j < 4; j++) {
        int ej = wid * 16 + kg * 4 + j;
        msg2[(size_t)ej * NH2 + l15] = (__bf16)c[j];
    }
}

// ---------------- per-dst aggregation: sum msgs + root-init + bias + relu ----------------
__global__ __launch_bounds__(256) void k_agg1(const int* __restrict__ row_start,
                                              const int* __restrict__ eperm,
                                              const __bf16* __restrict__ msg1,
                                              const __bf16* __restrict__ h0b,
                                              const float* __restrict__ root1,
                                              const float* __restrict__ bias1,
                                              __bf16* __restrict__ h1b) {
    int dst = blockIdx.x * 4 + (threadIdx.x >> 6);   // 30000 waves exactly
    int lane = threadIdx.x & 63;
    int col = lane & 31, half = lane >> 5;
    // init: h0[dst] @ root1, k split across halves
    float acc = 0.f;
    const __bf16* h = h0b + (size_t)dst * NEMB + half * 32;
    const float* rt = root1 + (size_t)half * 32 * NH1 + col;
#pragma unroll 8
    for (int k = 0; k < 32; k++) acc += (float)h[k] * rt[k * NH1];
    int s = row_start[dst], send = row_start[dst + 1];
    for (int i = s + half; i < send; i += 2) {
        int e = eperm[i];
        acc += (float)msg1[(size_t)e * NH1 + col];
    }
    acc += __shfl_xor(acc, 32);
    if (half == 0) {
        float v = acc + bias1[col];
        h1b[(size_t)dst * NH1 + col] = (__bf16)fmaxf(v, 0.f);
    }
}

__global__ __launch_bounds__(256) void k_agg2(const int* __restrict__ row_start,
                                              const int* __restrict__ eperm,
                                              const __bf16* __restrict__ msg2,
                                              const __bf16* __restrict__ h1b,
                                              const float* __restrict__ root2,
                                              const float* __restrict__ bias2,
                                              float* __restrict__ out) {
    int dst = blockIdx.x * 4 + (threadIdx.x >> 6);
    int lane = threadIdx.x & 63;
    int col = lane & 15, q = lane >> 4;              // 4 k/edge groups
    float acc = 0.f;
    const __bf16* h = h1b + (size_t)dst * NH1 + q * 8;
    const float* rt = root2 + (size_t)q * 8 * NH2 + col;
#pragma unroll
    for (int k = 0; k < 8; k++) acc += (float)h[k] * rt[k * NH2];
    int s = row_start[dst], send = row_start[dst + 1];
    for (int i = s + q; i < send; i += 4) {
        int e = eperm[i];
        acc += (float)msg2[(size_t)e * NH2 + col];
    }
    acc += __shfl_xor(acc, 32);
    acc += __shfl_xor(acc, 16);
    if (lane < 16) {
        out[(size_t)dst * NH2 + col] = fmaxf(acc + bias2[col], 0.f);
    }
}

// ---------------- launch ----------------
extern "C" void kernel_launch(void* const* d_in, const int* in_sizes, int n_in,
                              void* d_out, int out_size, void* d_ws, size_t ws_size,
                              hipStream_t stream) {
    const float* x      = (const float*)d_in[0];
    const int*   ei     = (const int*)d_in[1];
    const int*   et     = (const int*)d_in[2];
    const float* xnorm  = (const float*)d_in[4];
    const float* embed  = (const float*)d_in[5];
    const float* basis1 = (const float*)d_in[6];
    const float* att1   = (const float*)d_in[7];
    const float* root1  = (const float*)d_in[8];
    const float* bias1  = (const float*)d_in[9];
    const float* basis2 = (const float*)d_in[10];
    const float* att2   = (const float*)d_in[11];
    const float* root2  = (const float*)d_in[12];
    const float* bias2  = (const float*)d_in[13];
    float* out = (float*)d_out;

    char* ws = (char*)d_ws;
    __bf16* embT = (__bf16*)(ws + 0);              //   262,144
    __bf16* W1T  = (__bf16*)(ws + 262144);         //   262,144
    __bf16* W2T  = (__bf16*)(ws + 524288);         //    65,536
    __bf16* h0b  = (__bf16*)(ws + 589824);         // 3,840,000
    __bf16* h1b  = (__bf16*)(ws + 4429824);        // 1,920,000
    int*    deg  = (int*)   (ws + 6349824);        //   120,000
    int*    rs   = (int*)   (ws + 6469824);        //   120,064 (30001 ints + pad)
    int*    cur  = (int*)   (ws + 6589888);        //   120,000
    int*    eperm= (int*)   (ws + 6709888);        // 3,840,000
    __bf16* msg1 = (__bf16*)(ws + 10549888);       // 61,440,000
    __bf16* msg2 = (__bf16*)(ws + 71989888);       // 30,720,000  (end ~102.7 MB)

    k_prep   <<<644,  256,  0, stream>>>(embed, basis1, att1, basis2, att2, embT, W1T, W2T, deg);
    k_embed  <<<469,  256,  0, stream>>>(x, xnorm, embT, h0b);
    k_hist   <<<3750, 256,  0, stream>>>(ei, deg);
    k_scan   <<<1,    1024, 0, stream>>>(deg, rs, cur);
    k_scatter<<<3750, 256,  0, stream>>>(ei, cur, eperm);
    k_edge1m <<<15000,256,  0, stream>>>(ei, et, h0b, W1T, msg1);
    k_agg1   <<<7500, 256,  0, stream>>>(rs, eperm, msg1, h0b, root1, bias1, h1b);
    k_edge2m <<<15000,256,  0, stream>>>(ei, et, h1b, W2T, msg2);
    k_agg2   <<<7500, 256,  0, stream>>>(rs, eperm, msg2, h1b, root2, bias2, out);
}

// Round 3
// 378.827 us; speedup vs baseline: 1.1700x; 1.1700x over previous
//
#include <hip/hip_runtime.h>
#include <hip/hip_bf16.h>

#define NN   30000
#define EE   960000
#define IND  2048
#define NEMB 64
#define NH1  32
#define NH2  16
#define NET  64
#define NB   16

typedef __bf16 bf8 __attribute__((ext_vector_type(8)));
typedef __bf16 bf4 __attribute__((ext_vector_type(4)));
typedef __bf16 bf2 __attribute__((ext_vector_type(2)));
typedef float  f4  __attribute__((ext_vector_type(4)));

__device__ __forceinline__ bf8 bf8_zero() {
    bf8 z;
#pragma unroll
    for (int i = 0; i < 8; i++) z[i] = (__bf16)0.0f;
    return z;
}
__device__ __forceinline__ float blo(unsigned v) { return __uint_as_float(v << 16); }
__device__ __forceinline__ float bhi(unsigned v) { return __uint_as_float(v & 0xffff0000u); }

// ---------------- merged prep: embT + W1T + W2T + zero(deg) ----------------
__global__ __launch_bounds__(256) void k_prep(const float* __restrict__ embed,
                                              const float* __restrict__ basis1,
                                              const float* __restrict__ att1,
                                              const float* __restrict__ basis2,
                                              const float* __restrict__ att2,
                                              __bf16* __restrict__ embT,
                                              __bf16* __restrict__ W1T,
                                              __bf16* __restrict__ W2T,
                                              int* __restrict__ deg) {
    int b = blockIdx.x;
    if (b < 512) {
        int idx = b * 256 + threadIdx.x;        // embT[n][k] = embed[k][n]
        int n = idx >> 11, k = idx & 2047;
        embT[idx] = (__bf16)embed[k * NEMB + n];
    } else if (b < 576) {
        int r = b - 512;
        __shared__ float a[NB];
        if (threadIdx.x < NB) a[threadIdx.x] = att1[r * NB + threadIdx.x];
        __syncthreads();
        for (int idx = threadIdx.x; idx < NH1 * NEMB; idx += 256) {
            int o = idx >> 6, i = idx & 63;
            float acc = 0.f;
#pragma unroll
            for (int bb = 0; bb < NB; bb++) acc += a[bb] * basis1[(bb * NEMB + i) * NH1 + o];
            W1T[r * (NH1 * NEMB) + idx] = (__bf16)acc;
        }
    } else if (b < 640) {
        int r = b - 576;
        __shared__ float a[NB];
        if (threadIdx.x < NB) a[threadIdx.x] = att2[r * NB + threadIdx.x];
        __syncthreads();
        for (int idx = threadIdx.x; idx < NH2 * NH1; idx += 256) {
            int o = idx >> 5, i = idx & 31;
            float acc = 0.f;
#pragma unroll
            for (int bb = 0; bb < NB; bb++) acc += a[bb] * basis2[(bb * NH1 + i) * NH2 + o];
            W2T[r * (NH2 * NH1) + idx] = (__bf16)acc;
        }
    } else {
        for (int i = (b - 640) * 256 + threadIdx.x; i < NN; i += 4 * 256) deg[i] = 0;
    }
}

// ---------------- embed GEMM: h0 = (x @ embed)/x_norm -> bf16 ----------------
__global__ __launch_bounds__(256) void k_embed(const float* __restrict__ x,
                                               const float* __restrict__ xnorm,
                                               const __bf16* __restrict__ embT,
                                               __bf16* __restrict__ h0b) {
    int lane = threadIdx.x & 63;
    int wave = threadIdx.x >> 6;
    int rowbase = blockIdx.x * 64 + wave * 16;
    int l15 = lane & 15, kg = lane >> 4;
    int arow = rowbase + l15;
    int arow_c = arow < NN ? arow : NN - 1;
    const float*  xp = x + (size_t)arow_c * IND + kg * 8;
    const __bf16* bp = embT + (size_t)l15 * IND + kg * 8;
    f4 acc0 = (f4)0.0f, acc1 = (f4)0.0f, acc2 = (f4)0.0f, acc3 = (f4)0.0f;
#pragma unroll 2
    for (int k0 = 0; k0 < IND; k0 += 32) {
        float4 lo = *(const float4*)(xp + k0);
        float4 hi = *(const float4*)(xp + k0 + 4);
        bf8 av;
        av[0] = (__bf16)lo.x; av[1] = (__bf16)lo.y; av[2] = (__bf16)lo.z; av[3] = (__bf16)lo.w;
        av[4] = (__bf16)hi.x; av[5] = (__bf16)hi.y; av[6] = (__bf16)hi.z; av[7] = (__bf16)hi.w;
        bf8 b0 = *(const bf8*)(bp + k0);
        bf8 b1 = *(const bf8*)(bp + 16 * IND + k0);
        bf8 b2 = *(const bf8*)(bp + 32 * IND + k0);
        bf8 b3 = *(const bf8*)(bp + 48 * IND + k0);
        acc0 = __builtin_amdgcn_mfma_f32_16x16x32_bf16(av, b0, acc0, 0, 0, 0);
        acc1 = __builtin_amdgcn_mfma_f32_16x16x32_bf16(av, b1, acc1, 0, 0, 0);
        acc2 = __builtin_amdgcn_mfma_f32_16x16x32_bf16(av, b2, acc2, 0, 0, 0);
        acc3 = __builtin_amdgcn_mfma_f32_16x16x32_bf16(av, b3, acc3, 0, 0, 0);
    }
#pragma unroll
    for (int j = 0; j < 4; j++) {
        int r = rowbase + kg * 4 + j;
        if (r < NN) {
            float inv = 1.0f / xnorm[r];
            __bf16* hp = h0b + (size_t)r * NEMB + l15;
            hp[0]  = (__bf16)(acc0[j] * inv);
            hp[16] = (__bf16)(acc1[j] * inv);
            hp[32] = (__bf16)(acc2[j] * inv);
            hp[48] = (__bf16)(acc3[j] * inv);
        }
    }
}

// ---------------- CSR build (by dst) ----------------
__global__ __launch_bounds__(256) void k_hist(const int* __restrict__ ei, int* __restrict__ deg) {
    int e = blockIdx.x * 256 + threadIdx.x;
    atomicAdd(&deg[ei[EE + e]], 1);
}

// single block, 1024 threads, 30 contiguous elements each; ONE LDS scan.
__global__ __launch_bounds__(1024) void k_scan(const int* __restrict__ deg,
                                               int* __restrict__ row_start,
                                               int* __restrict__ cursor) {
    __shared__ int lds[1024];
    int t = threadIdx.x;
    const int PER = 30;
    int i0 = t * PER;
    int s = 0;
#pragma unroll
    for (int j = 0; j < PER; j++) {
        int i = i0 + j;
        if (i < NN) s += deg[i];
    }
    lds[t] = s;
    __syncthreads();
    for (int off = 1; off < 1024; off <<= 1) {
        int add = (t >= off) ? lds[t - off] : 0;
        __syncthreads();
        lds[t] += add;
        __syncthreads();
    }
    int run = lds[t] - s;        // exclusive prefix of this chunk
    for (int j = 0; j < PER; j++) {
        int i = i0 + j;
        if (i < NN) {
            row_start[i] = run;
            cursor[i]    = run;
            run += deg[i];
        }
    }
    if (t == 0) row_start[NN] = EE;
}

__global__ __launch_bounds__(256) void k_scatter(const int* __restrict__ ei,
                                                 int* __restrict__ cursor,
                                                 int* __restrict__ epos) {
    int e = blockIdx.x * 256 + threadIdx.x;
    int dst = ei[EE + e];
    epos[e] = atomicAdd(&cursor[dst], 1);   // CSR slot for edge e
}

// ---------------- edge message kernels: write msgs INTO CSR SLOTS ----------------
__global__ __launch_bounds__(256) void k_edge1m(const int* __restrict__ ei,
                                                const int* __restrict__ et,
                                                const int* __restrict__ epos,
                                                const __bf16* __restrict__ h0b,
                                                const __bf16* __restrict__ W1T,
                                                __bf16* __restrict__ msg1) {
    int wid = blockIdx.x * 4 + (threadIdx.x >> 6);
    int lane = threadIdx.x & 63;
    int l15 = lane & 15, kg = lane >> 4;
    int er = wid * 16 + l15;
    int my_et  = et[er];
    int my_src = ei[er];
    int my_pos = epos[er];
    const __bf16* hp = h0b + (size_t)my_src * NEMB + kg * 8;
    bf8 a0 = *(const bf8*)hp;
    bf8 a1 = *(const bf8*)(hp + 32);
    bf8 zero = bf8_zero();
    f4 c0 = (f4)0.0f, c1 = (f4)0.0f;
    int pos = 0;
    while (pos < 16) {
        int r = __shfl(my_et, pos);
        unsigned long long bl = __ballot(my_et == r);
        unsigned m16 = (unsigned)(bl & 0xFFFFull);
        int run = __builtin_ctz(~(m16 >> pos));
        int end = pos + run;
        const __bf16* wb = W1T + (size_t)r * (NH1 * NEMB) + (size_t)l15 * NEMB + kg * 8;
        bf8 b00 = *(const bf8*)(wb);
        bf8 b01 = *(const bf8*)(wb + 32);
        bf8 b10 = *(const bf8*)(wb + 16 * NEMB);
        bf8 b11 = *(const bf8*)(wb + 16 * NEMB + 32);
        bool use = (l15 >= pos) && (l15 < end);
        bf8 ua0 = use ? a0 : zero;
        bf8 ua1 = use ? a1 : zero;
        c0 = __builtin_amdgcn_mfma_f32_16x16x32_bf16(ua0, b00, c0, 0, 0, 0);
        c0 = __builtin_amdgcn_mfma_f32_16x16x32_bf16(ua1, b01, c0, 0, 0, 0);
        c1 = __builtin_amdgcn_mfma_f32_16x16x32_bf16(ua0, b10, c1, 0, 0, 0);
        c1 = __builtin_amdgcn_mfma_f32_16x16x32_bf16(ua1, b11, c1, 0, 0, 0);
        pos = end;
    }
#pragma unroll
    for (int j = 0; j < 4; j++) {
        int eidx = kg * 4 + j;
        int slot = __shfl(my_pos, eidx);
        __bf16* mp = msg1 + (size_t)slot * NH1;
        mp[l15]      = (__bf16)c0[j];
        mp[16 + l15] = (__bf16)c1[j];
    }
}

__global__ __launch_bounds__(256) void k_edge2m(const int* __restrict__ ei,
                                                const int* __restrict__ et,
                                                const int* __restrict__ epos,
                                                const __bf16* __restrict__ h1b,
                                                const __bf16* __restrict__ W2T,
                                                __bf16* __restrict__ msg2) {
    int wid = blockIdx.x * 4 + (threadIdx.x >> 6);
    int lane = threadIdx.x & 63;
    int l15 = lane & 15, kg = lane >> 4;
    int er = wid * 16 + l15;
    int my_et  = et[er];
    int my_src = ei[er];
    int my_pos = epos[er];
    bf8 a = *(const bf8*)(h1b + (size_t)my_src * NH1 + kg * 8);
    bf8 zero = bf8_zero();
    f4 c = (f4)0.0f;
    int pos = 0;
    while (pos < 16) {
        int r = __shfl(my_et, pos);
        unsigned long long bl = __ballot(my_et == r);
        unsigned m16 = (unsigned)(bl & 0xFFFFull);
        int run = __builtin_ctz(~(m16 >> pos));
        int end = pos + run;
        bf8 b = *(const bf8*)(W2T + (size_t)r * (NH2 * NH1) + (size_t)l15 * NH1 + kg * 8);
        bool use = (l15 >= pos) && (l15 < end);
        c = __builtin_amdgcn_mfma_f32_16x16x32_bf16(use ? a : zero, b, c, 0, 0, 0);
        pos = end;
    }
#pragma unroll
    for (int j = 0; j < 4; j++) {
        int eidx = kg * 4 + j;
        int slot = __shfl(my_pos, eidx);
        msg2[(size_t)slot * NH2 + l15] = (__bf16)c[j];
    }
}

// ---------------- per-dst aggregation: contiguous msg stream + root + bias + relu ----------------
__global__ __launch_bounds__(256) void k_agg1(const int* __restrict__ row_start,
                                              const unsigned* __restrict__ msg1,   // bf16x2 words
                                              const __bf16* __restrict__ h0b,
                                              const float* __restrict__ root1,
                                              const float* __restrict__ bias1,
                                              __bf16* __restrict__ h1b) {
    int dst = blockIdx.x * 4 + (threadIdx.x >> 6);
    int lane = threadIdx.x & 63;
    int c2 = lane & 15;          // column pair (2*c2, 2*c2+1)
    int m  = lane >> 4;          // msg sub-index / k-quarter
    float ax = 0.f, ay = 0.f;
    // root: k in [m*16, m*16+16)
    bf8 hv0 = *(const bf8*)(h0b + (size_t)dst * NEMB + m * 16);
    bf8 hv1 = *(const bf8*)(h0b + (size_t)dst * NEMB + m * 16 + 8);
    const float2* rt = (const float2*)root1;     // [64][16] float2
#pragma unroll
    for (int k = 0; k < 8; k++) {
        float a = (float)hv0[k];
        float2 w = rt[(size_t)(m * 16 + k) * 16 + c2];
        ax += a * w.x; ay += a * w.y;
    }
#pragma unroll
    for (int k = 0; k < 8; k++) {
        float a = (float)hv1[k];
        float2 w = rt[(size_t)(m * 16 + 8 + k) * 16 + c2];
        ax += a * w.x; ay += a * w.y;
    }
    // messages: contiguous rows [s, e), 4 msgs per wave-iter (256B)
    int s = row_start[dst], e = row_start[dst + 1];
    for (int i = s + m; i < e; i += 4) {
        unsigned v = msg1[(size_t)i * 16 + c2];
        ax += blo(v); ay += bhi(v);
    }
    ax += __shfl_xor(ax, 16); ay += __shfl_xor(ay, 16);
    ax += __shfl_xor(ax, 32); ay += __shfl_xor(ay, 32);
    if (m == 0) {
        float2 bsv = ((const float2*)bias1)[c2];
        bf2 st;
        st[0] = (__bf16)fmaxf(ax + bsv.x, 0.f);
        st[1] = (__bf16)fmaxf(ay + bsv.y, 0.f);
        *(bf2*)(h1b + (size_t)dst * NH1 + 2 * c2) = st;
    }
}

__global__ __launch_bounds__(256) void k_agg2(const int* __restrict__ row_start,
                                              const unsigned* __restrict__ msg2,   // bf16x2 words
                                              const __bf16* __restrict__ h1b,
                                              const float* __restrict__ root2,
                                              const float* __restrict__ bias2,
                                              float* __restrict__ out) {
    int dst = blockIdx.x * 4 + (threadIdx.x >> 6);
    int lane = threadIdx.x & 63;
    int c2 = lane & 7;           // column pair (2*c2, 2*c2+1)
    int m  = lane >> 3;          // msg sub-index / k-eighth (0..7)
    float ax = 0.f, ay = 0.f;
    // root: k in [m*4, m*4+4)
    bf4 hv = *(const bf4*)(h1b + (size_t)dst * NH1 + m * 4);
    const float2* rt = (const float2*)root2;     // [32][8] float2
#pragma unroll
    for (int k = 0; k < 4; k++) {
        float a = (float)hv[k];
        float2 w = rt[(size_t)(m * 4 + k) * 8 + c2];
        ax += a * w.x; ay += a * w.y;
    }
    // messages: 8 msgs per wave-iter (256B)
    int s = row_start[dst], e = row_start[dst + 1];
    for (int i = s + m; i < e; i += 8) {
        unsigned v = msg2[(size_t)i * 8 + c2];
        ax += blo(v); ay += bhi(v);
    }
    ax += __shfl_xor(ax, 8);  ay += __shfl_xor(ay, 8);
    ax += __shfl_xor(ax, 16); ay += __shfl_xor(ay, 16);
    ax += __shfl_xor(ax, 32); ay += __shfl_xor(ay, 32);
    if (m == 0) {
        float2 bsv = ((const float2*)bias2)[c2];
        float2 o;
        o.x = fmaxf(ax + bsv.x, 0.f);
        o.y = fmaxf(ay + bsv.y, 0.f);
        ((float2*)out)[(size_t)dst * 8 + c2] = o;
    }
}

// ---------------- launch ----------------
extern "C" void kernel_launch(void* const* d_in, const int* in_sizes, int n_in,
                              void* d_out, int out_size, void* d_ws, size_t ws_size,
                              hipStream_t stream) {
    const float* x      = (const float*)d_in[0];
    const int*   ei     = (const int*)d_in[1];
    const int*   et     = (const int*)d_in[2];
    const float* xnorm  = (const float*)d_in[4];
    const float* embed  = (const float*)d_in[5];
    const float* basis1 = (const float*)d_in[6];
    const float* att1   = (const float*)d_in[7];
    const float* root1  = (const float*)d_in[8];
    const float* bias1  = (const float*)d_in[9];
    const float* basis2 = (const float*)d_in[10];
    const float* att2   = (const float*)d_in[11];
    const float* root2  = (const float*)d_in[12];
    const float* bias2  = (const float*)d_in[13];
    float* out = (float*)d_out;

    char* ws = (char*)d_ws;
    __bf16* embT = (__bf16*)(ws + 0);              //   262,144
    __bf16* W1T  = (__bf16*)(ws + 262144);         //   262,144
    __bf16* W2T  = (__bf16*)(ws + 524288);         //    65,536
    __bf16* h0b  = (__bf16*)(ws + 589824);         // 3,840,000
    __bf16* h1b  = (__bf16*)(ws + 4429824);        // 1,920,000
    int*    deg  = (int*)   (ws + 6349824);        //   120,000
    int*    rs   = (int*)   (ws + 6469824);        //   120,064
    int*    cur  = (int*)   (ws + 6589888);        //   120,000
    int*    epos = (int*)   (ws + 6709888);        // 3,840,000
    __bf16* msg1 = (__bf16*)(ws + 10549888);       // 61,440,000
    __bf16* msg2 = (__bf16*)(ws + 71989888);       // 30,720,000  (end ~102.7 MB)

    k_prep   <<<644,  256,  0, stream>>>(embed, basis1, att1, basis2, att2, embT, W1T, W2T, deg);
    k_hist   <<<3750, 256,  0, stream>>>(ei, deg);
    k_scan   <<<1,    1024, 0, stream>>>(deg, rs, cur);
    k_scatter<<<3750, 256,  0, stream>>>(ei, cur, epos);
    k_embed  <<<469,  256,  0, stream>>>(x, xnorm, embT, h0b);
    k_edge1m <<<15000,256,  0, stream>>>(ei, et, epos, h0b, W1T, msg1);
    k_agg1   <<<7500, 256,  0, stream>>>(rs, (const unsigned*)msg1, h0b, root1, bias1, h1b);
    k_edge2m <<<15000,256,  0, stream>>>(ei, et, epos, h1b, W2T, msg2);
    k_agg2   <<<7500, 256,  0, stream>>>(rs, (const unsigned*)msg2, h1b, root2, bias2, out);
}

// Round 4
// 366.402 us; speedup vs baseline: 1.2097x; 1.0339x over previous
//
#include <hip/hip_runtime.h>
#include <hip/hip_bf16.h>

#define NN   30000
#define EE   960000
#define IND  2048
#define NEMB 64
#define NH1  32
#define NH2  16
#define NET  64
#define NB   16

typedef __bf16 bf8 __attribute__((ext_vector_type(8)));
typedef __bf16 bf4 __attribute__((ext_vector_type(4)));
typedef float  f4  __attribute__((ext_vector_type(4)));

__device__ __forceinline__ bf8 bf8_zero() {
    bf8 z;
#pragma unroll
    for (int i = 0; i < 8; i++) z[i] = (__bf16)0.0f;
    return z;
}
__device__ __forceinline__ float blo(unsigned v) { return __uint_as_float(v << 16); }
__device__ __forceinline__ float bhi(unsigned v) { return __uint_as_float(v & 0xffff0000u); }

// ---------------- prep (embT/W1T/W2T) + hist, grid-split ----------------
__global__ __launch_bounds__(256) void k_prep_hist(const float* __restrict__ embed,
                                                   const float* __restrict__ basis1,
                                                   const float* __restrict__ att1,
                                                   const float* __restrict__ basis2,
                                                   const float* __restrict__ att2,
                                                   const int* __restrict__ ei,
                                                   __bf16* __restrict__ embT,
                                                   __bf16* __restrict__ W1T,
                                                   __bf16* __restrict__ W2T,
                                                   int* __restrict__ deg) {
    int b = blockIdx.x;
    if (b < 512) {
        int idx = b * 256 + threadIdx.x;        // embT[n][k] = embed[k][n]
        int n = idx >> 11, k = idx & 2047;
        embT[idx] = (__bf16)embed[k * NEMB + n];
    } else if (b < 576) {
        int r = b - 512;
        __shared__ float a[NB];
        if (threadIdx.x < NB) a[threadIdx.x] = att1[r * NB + threadIdx.x];
        __syncthreads();
        for (int idx = threadIdx.x; idx < NH1 * NEMB; idx += 256) {
            int o = idx >> 6, i = idx & 63;
            float acc = 0.f;
#pragma unroll
            for (int bb = 0; bb < NB; bb++) acc += a[bb] * basis1[(bb * NEMB + i) * NH1 + o];
            W1T[r * (NH1 * NEMB) + idx] = (__bf16)acc;
        }
    } else if (b < 640) {
        int r = b - 576;
        __shared__ float a[NB];
        if (threadIdx.x < NB) a[threadIdx.x] = att2[r * NB + threadIdx.x];
        __syncthreads();
        for (int idx = threadIdx.x; idx < NH2 * NH1; idx += 256) {
            int o = idx >> 5, i = idx & 31;
            float acc = 0.f;
#pragma unroll
            for (int bb = 0; bb < NB; bb++) acc += a[bb] * basis2[(bb * NH1 + i) * NH2 + o];
            W2T[r * (NH2 * NH1) + idx] = (__bf16)acc;
        }
    } else {
        for (int e = (b - 640) * 256 + threadIdx.x; e < EE; e += 512 * 256)
            atomicAdd(&deg[ei[EE + e]], 1);
    }
}

// ---------------- scan (block 0) + embed GEMM K-split (blocks 1..938) ----------------
__global__ __launch_bounds__(256) void k_scan_embed(const int* __restrict__ deg,
                                                    int* __restrict__ rs,
                                                    int* __restrict__ cur,
                                                    const float* __restrict__ x,
                                                    const float* __restrict__ xnorm,
                                                    const __bf16* __restrict__ embT,
                                                    __bf16* __restrict__ h0b) {
    __shared__ float smem[4 * 16 * 68];          // 17408 B (waves × 16 rows × 68 f32)
    if (blockIdx.x == 0) {
        int* lds = (int*)smem;
        int t = threadIdx.x;
        const int PER = 118;                      // 256*118 = 30208 >= NN
        int i0 = t * PER;
        int s = 0;
        for (int j = 0; j < PER; j++) { int i = i0 + j; if (i < NN) s += deg[i]; }
        lds[t] = s;
        __syncthreads();
        for (int off = 1; off < 256; off <<= 1) {
            int add = (t >= off) ? lds[t - off] : 0;
            __syncthreads();
            lds[t] += add;
            __syncthreads();
        }
        int run = lds[t] - s;
        for (int j = 0; j < PER; j++) {
            int i = i0 + j;
            if (i < NN) { rs[i] = run; cur[i] = run; run += deg[i]; }
        }
        if (t == 0) rs[NN] = EE;
        return;
    }
    // embed: 2 tiles/block (16 rows each), 2 waves per tile split K=1024 each
    int lane = threadIdx.x & 63;
    int wave = threadIdx.x >> 6;
    int tile = wave >> 1, kh = wave & 1;
    int l15 = lane & 15, kg = lane >> 4;
    int rowbase = (blockIdx.x - 1) * 32 + tile * 16;
    int arow = rowbase + l15;
    int arow_c = arow < NN ? arow : NN - 1;
    const float*  xp = x + (size_t)arow_c * IND + kh * 1024 + kg * 8;
    const __bf16* bp = embT + (size_t)l15 * IND + kh * 1024 + kg * 8;
    f4 acc0 = (f4)0.0f, acc1 = (f4)0.0f, acc2 = (f4)0.0f, acc3 = (f4)0.0f;
#pragma unroll 2
    for (int k0 = 0; k0 < 1024; k0 += 32) {
        float4 lo = *(const float4*)(xp + k0);
        float4 hi = *(const float4*)(xp + k0 + 4);
        bf8 av;
        av[0] = (__bf16)lo.x; av[1] = (__bf16)lo.y; av[2] = (__bf16)lo.z; av[3] = (__bf16)lo.w;
        av[4] = (__bf16)hi.x; av[5] = (__bf16)hi.y; av[6] = (__bf16)hi.z; av[7] = (__bf16)hi.w;
        bf8 b0 = *(const bf8*)(bp + k0);
        bf8 b1 = *(const bf8*)(bp + 16 * IND + k0);
        bf8 b2 = *(const bf8*)(bp + 32 * IND + k0);
        bf8 b3 = *(const bf8*)(bp + 48 * IND + k0);
        acc0 = __builtin_amdgcn_mfma_f32_16x16x32_bf16(av, b0, acc0, 0, 0, 0);
        acc1 = __builtin_amdgcn_mfma_f32_16x16x32_bf16(av, b1, acc1, 0, 0, 0);
        acc2 = __builtin_amdgcn_mfma_f32_16x16x32_bf16(av, b2, acc2, 0, 0, 0);
        acc3 = __builtin_amdgcn_mfma_f32_16x16x32_bf16(av, b3, acc3, 0, 0, 0);
    }
    float* wsm = smem + wave * (16 * 68);
#pragma unroll
    for (int j = 0; j < 4; j++) {
        int r = kg * 4 + j;
        wsm[r * 68 + l15]      = acc0[j];
        wsm[r * 68 + 16 + l15] = acc1[j];
        wsm[r * 68 + 32 + l15] = acc2[j];
        wsm[r * 68 + 48 + l15] = acc3[j];
    }
    __syncthreads();
    int t = threadIdx.x;
    int tl = t >> 7, row = (t >> 3) & 15, c8 = t & 7;
    int orow = (blockIdx.x - 1) * 32 + tl * 16 + row;
    if (orow < NN) {
        const float* pa = smem + (2 * tl) * (16 * 68) + row * 68 + c8 * 8;
        const float* pb = pa + 16 * 68;
        float inv = 1.0f / xnorm[orow];
        bf8 o;
#pragma unroll
        for (int k = 0; k < 8; k++) o[k] = (__bf16)((pa[k] + pb[k]) * inv);
        *(bf8*)(h0b + (size_t)orow * NEMB + c8 * 8) = o;
    }
}

// ---------------- edge layer 1: MFMA batch + fused slot-atomic + LDS-transposed store ----------------
__global__ __launch_bounds__(256) void k_edge1(const int* __restrict__ ei,
                                               const int* __restrict__ et,
                                               const __bf16* __restrict__ h0b,
                                               const __bf16* __restrict__ W1T,
                                               int* __restrict__ cur,
                                               int* __restrict__ epos,
                                               __bf16* __restrict__ msg1) {
    __shared__ __bf16 lt[4][16][32];
    int wave = threadIdx.x >> 6, lane = threadIdx.x & 63;
    int l15 = lane & 15, kg = lane >> 4;
    int wid = blockIdx.x * 4 + wave;             // 30000 waves, 32 edges each
    int row = lane >> 2, q = lane & 3;
#pragma unroll
    for (int b = 0; b < 2; b++) {
        int er = wid * 32 + b * 16 + l15;
        int my_et  = et[er];
        int my_src = ei[er];
        const __bf16* hp = h0b + (size_t)my_src * NEMB + kg * 8;
        bf8 a0 = *(const bf8*)hp;
        bf8 a1 = *(const bf8*)(hp + 32);
        bf8 zero = bf8_zero();
        f4 c0 = (f4)0.0f, c1 = (f4)0.0f;
        int pos = 0;
        while (pos < 16) {
            int r = __shfl(my_et, pos);
            unsigned long long bl = __ballot(my_et == r);
            unsigned m16 = (unsigned)(bl & 0xFFFFull);
            int run = __builtin_ctz(~(m16 >> pos));
            int end = pos + run;
            const __bf16* wb = W1T + (size_t)r * (NH1 * NEMB) + (size_t)l15 * NEMB + kg * 8;
            bf8 b00 = *(const bf8*)(wb);
            bf8 b01 = *(const bf8*)(wb + 32);
            bf8 b10 = *(const bf8*)(wb + 16 * NEMB);
            bf8 b11 = *(const bf8*)(wb + 16 * NEMB + 32);
            bool use = (l15 >= pos) && (l15 < end);
            bf8 ua0 = use ? a0 : zero;
            bf8 ua1 = use ? a1 : zero;
            c0 = __builtin_amdgcn_mfma_f32_16x16x32_bf16(ua0, b00, c0, 0, 0, 0);
            c0 = __builtin_amdgcn_mfma_f32_16x16x32_bf16(ua1, b01, c0, 0, 0, 0);
            c1 = __builtin_amdgcn_mfma_f32_16x16x32_bf16(ua0, b10, c1, 0, 0, 0);
            c1 = __builtin_amdgcn_mfma_f32_16x16x32_bf16(ua1, b11, c1, 0, 0, 0);
            pos = end;
        }
        int slotv = 0;
        if (kg == 0) {
            slotv = atomicAdd(&cur[ei[EE + er]], 1);
            epos[er] = slotv;
        }
#pragma unroll
        for (int j = 0; j < 4; j++) {
            lt[wave][kg * 4 + j][l15]      = (__bf16)c0[j];
            lt[wave][kg * 4 + j][16 + l15] = (__bf16)c1[j];
        }
        int slot = __shfl(slotv, row);           // lane `row` (<16) holds edge row's slot
        bf8 v = *(const bf8*)&lt[wave][row][q * 8];
        *(bf8*)(msg1 + (size_t)slot * NH1 + q * 8) = v;
    }
}

// ---------------- edge layer 2 ----------------
__global__ __launch_bounds__(256) void k_edge2(const int* __restrict__ ei,
                                               const int* __restrict__ et,
                                               const int* __restrict__ epos,
                                               const __bf16* __restrict__ h1b,
                                               const __bf16* __restrict__ W2T,
                                               __bf16* __restrict__ msg2) {
    __shared__ __bf16 lt[4][16][16];
    int wave = threadIdx.x >> 6, lane = threadIdx.x & 63;
    int l15 = lane & 15, kg = lane >> 4;
    int wid = blockIdx.x * 4 + wave;
    int row = lane >> 2, q = lane & 3;
#pragma unroll
    for (int b = 0; b < 2; b++) {
        int er = wid * 32 + b * 16 + l15;
        int my_et  = et[er];
        int my_src = ei[er];
        int slotv  = epos[er];
        bf8 a = *(const bf8*)(h1b + (size_t)my_src * NH1 + kg * 8);
        bf8 zero = bf8_zero();
        f4 c = (f4)0.0f;
        int pos = 0;
        while (pos < 16) {
            int r = __shfl(my_et, pos);
            unsigned long long bl = __ballot(my_et == r);
            unsigned m16 = (unsigned)(bl & 0xFFFFull);
            int run = __builtin_ctz(~(m16 >> pos));
            int end = pos + run;
            bf8 bb = *(const bf8*)(W2T + (size_t)r * (NH2 * NH1) + (size_t)l15 * NH1 + kg * 8);
            bool use = (l15 >= pos) && (l15 < end);
            c = __builtin_amdgcn_mfma_f32_16x16x32_bf16(use ? a : zero, bb, c, 0, 0, 0);
            pos = end;
        }
#pragma unroll
        for (int j = 0; j < 4; j++) lt[wave][kg * 4 + j][l15] = (__bf16)c[j];
        int slot = __shfl(slotv, row);
        bf4 v = *(const bf4*)&lt[wave][row][q * 4];
        *(bf4*)(msg2 + (size_t)slot * NH2 + q * 4) = v;
    }
}

// ---------------- per-dst aggregation (stream) + root + bias + relu ----------------
__global__ __launch_bounds__(256) void k_agg1(const int* __restrict__ row_start,
                                              const unsigned* __restrict__ msg1,   // bf16x2 words
                                              const __bf16* __restrict__ h0b,
                                              const float* __restrict__ root1,
                                              const float* __restrict__ bias1,
                                              __bf16* __restrict__ h1b) {
    int dst = blockIdx.x * 4 + (threadIdx.x >> 6);
    int lane = threadIdx.x & 63;
    int c2 = lane & 15;
    int m  = lane >> 4;
    float ax = 0.f, ay = 0.f;
    bf8 hv0 = *(const bf8*)(h0b + (size_t)dst * NEMB + m * 16);
    bf8 hv1 = *(const bf8*)(h0b + (size_t)dst * NEMB + m * 16 + 8);
    const float2* rt = (const float2*)root1;
#pragma unroll
    for (int k = 0; k < 8; k++) {
        float a = (float)hv0[k];
        float2 w = rt[(size_t)(m * 16 + k) * 16 + c2];
        ax += a * w.x; ay += a * w.y;
    }
#pragma unroll
    for (int k = 0; k < 8; k++) {
        float a = (float)hv1[k];
        float2 w = rt[(size_t)(m * 16 + 8 + k) * 16 + c2];
        ax += a * w.x; ay += a * w.y;
    }
    int s = row_start[dst], e = row_start[dst + 1];
    for (int i = s + m; i < e; i += 4) {
        unsigned v = msg1[(size_t)i * 16 + c2];
        ax += blo(v); ay += bhi(v);
    }
    ax += __shfl_xor(ax, 16); ay += __shfl_xor(ay, 16);
    ax += __shfl_xor(ax, 32); ay += __shfl_xor(ay, 32);
    if (m == 0) {
        float2 bsv = ((const float2*)bias1)[c2];
        __bf16 o0 = (__bf16)fmaxf(ax + bsv.x, 0.f);
        __bf16 o1 = (__bf16)fmaxf(ay + bsv.y, 0.f);
        __bf16* hp = h1b + (size_t)dst * NH1 + 2 * c2;
        hp[0] = o0; hp[1] = o1;
    }
}

__global__ __launch_bounds__(256) void k_agg2(const int* __restrict__ row_start,
                                              const unsigned* __restrict__ msg2,   // bf16x2 words
                                              const __bf16* __restrict__ h1b,
                                              const float* __restrict__ root2,
                                              const float* __restrict__ bias2,
                                              float* __restrict__ out) {
    int dst = blockIdx.x * 4 + (threadIdx.x >> 6);
    int lane = threadIdx.x & 63;
    int c2 = lane & 7;
    int m  = lane >> 3;
    float ax = 0.f, ay = 0.f;
    bf4 hv = *(const bf4*)(h1b + (size_t)dst * NH1 + m * 4);
    const float2* rt = (const float2*)root2;
#pragma unroll
    for (int k = 0; k < 4; k++) {
        float a = (float)hv[k];
        float2 w = rt[(size_t)(m * 4 + k) * 8 + c2];
        ax += a * w.x; ay += a * w.y;
    }
    int s = row_start[dst], e = row_start[dst + 1];
    for (int i = s + m; i < e; i += 8) {
        unsigned v = msg2[(size_t)i * 8 + c2];
        ax += blo(v); ay += bhi(v);
    }
    ax += __shfl_xor(ax, 8);  ay += __shfl_xor(ay, 8);
    ax += __shfl_xor(ax, 16); ay += __shfl_xor(ay, 16);
    ax += __shfl_xor(ax, 32); ay += __shfl_xor(ay, 32);
    if (m == 0) {
        float2 bsv = ((const float2*)bias2)[c2];
        float2 o;
        o.x = fmaxf(ax + bsv.x, 0.f);
        o.y = fmaxf(ay + bsv.y, 0.f);
        ((float2*)out)[(size_t)dst * 8 + c2] = o;
    }
}

// ---------------- launch ----------------
extern "C" void kernel_launch(void* const* d_in, const int* in_sizes, int n_in,
                              void* d_out, int out_size, void* d_ws, size_t ws_size,
                              hipStream_t stream) {
    const float* x      = (const float*)d_in[0];
    const int*   ei     = (const int*)d_in[1];
    const int*   et     = (const int*)d_in[2];
    const float* xnorm  = (const float*)d_in[4];
    const float* embed  = (const float*)d_in[5];
    const float* basis1 = (const float*)d_in[6];
    const float* att1   = (const float*)d_in[7];
    const float* root1  = (const float*)d_in[8];
    const float* bias1  = (const float*)d_in[9];
    const float* basis2 = (const float*)d_in[10];
    const float* att2   = (const float*)d_in[11];
    const float* root2  = (const float*)d_in[12];
    const float* bias2  = (const float*)d_in[13];
    float* out = (float*)d_out;

    char* ws = (char*)d_ws;
    __bf16* embT = (__bf16*)(ws + 0);              //   262,144
    __bf16* W1T  = (__bf16*)(ws + 262144);         //   262,144
    __bf16* W2T  = (__bf16*)(ws + 524288);         //    65,536
    __bf16* h0b  = (__bf16*)(ws + 589824);         // 3,840,000
    __bf16* h1b  = (__bf16*)(ws + 4429824);        // 1,920,000
    int*    deg  = (int*)   (ws + 6349824);        //   120,000
    int*    rs   = (int*)   (ws + 6469824);        //   120,064
    int*    cur  = (int*)   (ws + 6589888);        //   120,000
    int*    epos = (int*)   (ws + 6709888);        // 3,840,000
    __bf16* msg1 = (__bf16*)(ws + 10549888);       // 61,440,000
    __bf16* msg2 = (__bf16*)(ws + 71989888);       // 30,720,000  (end ~102.7 MB)

    hipMemsetAsync(deg, 0, NN * sizeof(int), stream);
    k_prep_hist <<<1152, 256, 0, stream>>>(embed, basis1, att1, basis2, att2, ei,
                                           embT, W1T, W2T, deg);
    k_scan_embed<<<939,  256, 0, stream>>>(deg, rs, cur, x, xnorm, embT, h0b);
    k_edge1     <<<7500, 256, 0, stream>>>(ei, et, h0b, W1T, cur, epos, msg1);
    k_agg1      <<<7500, 256, 0, stream>>>(rs, (const unsigned*)msg1, h0b, root1, bias1, h1b);
    k_edge2     <<<7500, 256, 0, stream>>>(ei, et, epos, h1b, W2T, msg2);
    k_agg2      <<<7500, 256, 0, stream>>>(rs, (const unsigned*)msg2, h1b, root2, bias2, out);
}

// Round 5
// 338.958 us; speedup vs baseline: 1.3076x; 1.0810x over previous
//
#include <hip/hip_runtime.h>
#include <hip/hip_bf16.h>

#define NN   30000
#define EE   960000
#define IND  2048
#define NEMB 64
#define NH1  32
#define NH2  16
#define NET  64
#define NB   16

#define APAD 2056   // LDS row stride (bf16) for 16x2048 A panel

typedef __bf16 bf8 __attribute__((ext_vector_type(8)));
typedef __bf16 bf4 __attribute__((ext_vector_type(4)));
typedef float  f4  __attribute__((ext_vector_type(4)));

__device__ __forceinline__ bf8 bf8_zero() {
    bf8 z;
#pragma unroll
    for (int i = 0; i < 8; i++) z[i] = (__bf16)0.0f;
    return z;
}
__device__ __forceinline__ float blo(unsigned v) { return __uint_as_float(v << 16); }
__device__ __forceinline__ float bhi(unsigned v) { return __uint_as_float(v & 0xffff0000u); }

// ---------------- prep (embT/W1T/W2T) + hist, grid-split ----------------
__global__ __launch_bounds__(256) void k_prep_hist(const float* __restrict__ embed,
                                                   const float* __restrict__ basis1,
                                                   const float* __restrict__ att1,
                                                   const float* __restrict__ basis2,
                                                   const float* __restrict__ att2,
                                                   const int* __restrict__ ei,
                                                   __bf16* __restrict__ embT,
                                                   __bf16* __restrict__ W1T,
                                                   __bf16* __restrict__ W2T,
                                                   int* __restrict__ deg) {
    int b = blockIdx.x;
    if (b < 512) {
        int idx = b * 256 + threadIdx.x;        // embT[n][k] = embed[k][n]
        int n = idx >> 11, k = idx & 2047;
        embT[idx] = (__bf16)embed[k * NEMB + n];
    } else if (b < 576) {
        int r = b - 512;
        __shared__ float a[NB];
        if (threadIdx.x < NB) a[threadIdx.x] = att1[r * NB + threadIdx.x];
        __syncthreads();
        for (int idx = threadIdx.x; idx < NH1 * NEMB; idx += 256) {
            int o = idx >> 6, i = idx & 63;
            float acc = 0.f;
#pragma unroll
            for (int bb = 0; bb < NB; bb++) acc += a[bb] * basis1[(bb * NEMB + i) * NH1 + o];
            W1T[r * (NH1 * NEMB) + idx] = (__bf16)acc;
        }
    } else if (b < 640) {
        int r = b - 576;
        __shared__ float a[NB];
        if (threadIdx.x < NB) a[threadIdx.x] = att2[r * NB + threadIdx.x];
        __syncthreads();
        for (int idx = threadIdx.x; idx < NH2 * NH1; idx += 256) {
            int o = idx >> 5, i = idx & 31;
            float acc = 0.f;
#pragma unroll
            for (int bb = 0; bb < NB; bb++) acc += a[bb] * basis2[(bb * NH1 + i) * NH2 + o];
            W2T[r * (NH2 * NH1) + idx] = (__bf16)acc;
        }
    } else {
        for (int e = (b - 640) * 256 + threadIdx.x; e < EE; e += 512 * 256)
            atomicAdd(&deg[ei[EE + e]], 1);
    }
}

// ---------------- scan (block 0) + LDS-staged embed GEMM (blocks 1..1875) ----------------
// Per block: 16 rows x 64 cols, K=2048. A panel staged to LDS with fully
// sequential 1KB wave-loads (DRAM-friendly); 4 waves compute one 16x16
// col-block each from LDS A + L2-hot embT B.
__global__ __launch_bounds__(256) void k_scan_embed(const int* __restrict__ deg,
                                                    int* __restrict__ rs,
                                                    int* __restrict__ cur,
                                                    const float* __restrict__ x,
                                                    const float* __restrict__ xnorm,
                                                    const __bf16* __restrict__ embT,
                                                    __bf16* __restrict__ h0b) {
    __shared__ __align__(16) __bf16 As[16][APAD];   // 65,792 B
    if (blockIdx.x == 0) {
        int* lds = (int*)&As[0][0];
        int t = threadIdx.x;
        const int PER = 118;                      // 256*118 = 30208 >= NN
        int i0 = t * PER;
        int s = 0;
        for (int j = 0; j < PER; j++) { int i = i0 + j; if (i < NN) s += deg[i]; }
        lds[t] = s;
        __syncthreads();
        for (int off = 1; off < 256; off <<= 1) {
            int add = (t >= off) ? lds[t - off] : 0;
            __syncthreads();
            lds[t] += add;
            __syncthreads();
        }
        int run = lds[t] - s;
        for (int j = 0; j < PER; j++) {
            int i = i0 + j;
            if (i < NN) { rs[i] = run; cur[i] = run; run += deg[i]; }
        }
        if (t == 0) rs[NN] = EE;
        return;
    }
    int wave = threadIdx.x >> 6, lane = threadIdx.x & 63;
    int rowbase = (blockIdx.x - 1) * 16;
    // ---- stage: wave w stages local rows 4w..4w+3, sequential 1KB trips ----
    const float* xb = x + (size_t)(rowbase + wave * 4) * IND;
#pragma unroll 8
    for (int trip = 0; trip < 32; trip++) {
        int r = trip >> 3;                        // local row within wave's 4
        int off = (trip & 7) * 256 + lane * 4;    // float index in row
        float4 v = *(const float4*)(xb + (size_t)r * IND + off);
        bf4 o;
        o[0] = (__bf16)v.x; o[1] = (__bf16)v.y; o[2] = (__bf16)v.z; o[3] = (__bf16)v.w;
        *(bf4*)(&As[wave * 4 + r][off]) = o;
    }
    __syncthreads();
    // ---- compute: wave w -> cols [w*16, w*16+16) ----
    int l15 = lane & 15, kg = lane >> 4;
    const __bf16* bp = embT + (size_t)(wave * 16 + l15) * IND + kg * 8;
    const __bf16* ap = &As[l15][kg * 8];
    f4 acc = (f4)0.0f;
#pragma unroll 4
    for (int k0 = 0; k0 < IND; k0 += 32) {
        bf8 a = *(const bf8*)(ap + k0);
        bf8 b = *(const bf8*)(bp + k0);
        acc = __builtin_amdgcn_mfma_f32_16x16x32_bf16(a, b, acc, 0, 0, 0);
    }
#pragma unroll
    for (int j = 0; j < 4; j++) {
        int row = rowbase + kg * 4 + j;           // C row = (lane>>4)*4 + reg
        float inv = 1.0f / xnorm[row];
        h0b[(size_t)row * NEMB + wave * 16 + l15] = (__bf16)(acc[j] * inv);
    }
}

// ---------------- edge layer 1: MFMA batch + fused slot-atomic + LDS-transposed store ----------------
__global__ __launch_bounds__(256) void k_edge1(const int* __restrict__ ei,
                                               const int* __restrict__ et,
                                               const __bf16* __restrict__ h0b,
                                               const __bf16* __restrict__ W1T,
                                               int* __restrict__ cur,
                                               int* __restrict__ epos,
                                               __bf16* __restrict__ msg1) {
    __shared__ __bf16 lt[4][16][32];
    int wave = threadIdx.x >> 6, lane = threadIdx.x & 63;
    int l15 = lane & 15, kg = lane >> 4;
    int wid = blockIdx.x * 4 + wave;             // 30000 waves, 32 edges each
    int row = lane >> 2, q = lane & 3;
#pragma unroll
    for (int b = 0; b < 2; b++) {
        int er = wid * 32 + b * 16 + l15;
        int my_et  = et[er];
        int my_src = ei[er];
        const __bf16* hp = h0b + (size_t)my_src * NEMB + kg * 8;
        bf8 a0 = *(const bf8*)hp;
        bf8 a1 = *(const bf8*)(hp + 32);
        bf8 zero = bf8_zero();
        f4 c0 = (f4)0.0f, c1 = (f4)0.0f;
        int pos = 0;
        while (pos < 16) {
            int r = __shfl(my_et, pos);
            unsigned long long bl = __ballot(my_et == r);
            unsigned m16 = (unsigned)(bl & 0xFFFFull);
            int run = __builtin_ctz(~(m16 >> pos));
            int end = pos + run;
            const __bf16* wb = W1T + (size_t)r * (NH1 * NEMB) + (size_t)l15 * NEMB + kg * 8;
            bf8 b00 = *(const bf8*)(wb);
            bf8 b01 = *(const bf8*)(wb + 32);
            bf8 b10 = *(const bf8*)(wb + 16 * NEMB);
            bf8 b11 = *(const bf8*)(wb + 16 * NEMB + 32);
            bool use = (l15 >= pos) && (l15 < end);
            bf8 ua0 = use ? a0 : zero;
            bf8 ua1 = use ? a1 : zero;
            c0 = __builtin_amdgcn_mfma_f32_16x16x32_bf16(ua0, b00, c0, 0, 0, 0);
            c0 = __builtin_amdgcn_mfma_f32_16x16x32_bf16(ua1, b01, c0, 0, 0, 0);
            c1 = __builtin_amdgcn_mfma_f32_16x16x32_bf16(ua0, b10, c1, 0, 0, 0);
            c1 = __builtin_amdgcn_mfma_f32_16x16x32_bf16(ua1, b11, c1, 0, 0, 0);
            pos = end;
        }
        int slotv = 0;
        if (kg == 0) {
            slotv = atomicAdd(&cur[ei[EE + er]], 1);
            epos[er] = slotv;
        }
#pragma unroll
        for (int j = 0; j < 4; j++) {
            lt[wave][kg * 4 + j][l15]      = (__bf16)c0[j];
            lt[wave][kg * 4 + j][16 + l15] = (__bf16)c1[j];
        }
        int slot = __shfl(slotv, row);           // lane `row` (<16) holds edge row's slot
        bf8 v = *(const bf8*)&lt[wave][row][q * 8];
        *(bf8*)(msg1 + (size_t)slot * NH1 + q * 8) = v;
    }
}

// ---------------- edge layer 2 ----------------
__global__ __launch_bounds__(256) void k_edge2(const int* __restrict__ ei,
                                               const int* __restrict__ et,
                                               const int* __restrict__ epos,
                                               const __bf16* __restrict__ h1b,
                                               const __bf16* __restrict__ W2T,
                                               __bf16* __restrict__ msg2) {
    __shared__ __bf16 lt[4][16][16];
    int wave = threadIdx.x >> 6, lane = threadIdx.x & 63;
    int l15 = lane & 15, kg = lane >> 4;
    int wid = blockIdx.x * 4 + wave;
    int row = lane >> 2, q = lane & 3;
#pragma unroll
    for (int b = 0; b < 2; b++) {
        int er = wid * 32 + b * 16 + l15;
        int my_et  = et[er];
        int my_src = ei[er];
        int slotv  = epos[er];
        bf8 a = *(const bf8*)(h1b + (size_t)my_src * NH1 + kg * 8);
        bf8 zero = bf8_zero();
        f4 c = (f4)0.0f;
        int pos = 0;
        while (pos < 16) {
            int r = __shfl(my_et, pos);
            unsigned long long bl = __ballot(my_et == r);
            unsigned m16 = (unsigned)(bl & 0xFFFFull);
            int run = __builtin_ctz(~(m16 >> pos));
            int end = pos + run;
            bf8 bb = *(const bf8*)(W2T + (size_t)r * (NH2 * NH1) + (size_t)l15 * NH1 + kg * 8);
            bool use = (l15 >= pos) && (l15 < end);
            c = __builtin_amdgcn_mfma_f32_16x16x32_bf16(use ? a : zero, bb, c, 0, 0, 0);
            pos = end;
        }
#pragma unroll
        for (int j = 0; j < 4; j++) lt[wave][kg * 4 + j][l15] = (__bf16)c[j];
        int slot = __shfl(slotv, row);
        bf4 v = *(const bf4*)&lt[wave][row][q * 4];
        *(bf4*)(msg2 + (size_t)slot * NH2 + q * 4) = v;
    }
}

// ---------------- per-dst aggregation (stream) + root + bias + relu ----------------
__global__ __launch_bounds__(256) void k_agg1(const int* __restrict__ row_start,
                                              const unsigned* __restrict__ msg1,   // bf16x2 words
                                              const __bf16* __restrict__ h0b,
                                              const float* __restrict__ root1,
                                              const float* __restrict__ bias1,
                                              __bf16* __restrict__ h1b) {
    int dst = blockIdx.x * 4 + (threadIdx.x >> 6);
    int lane = threadIdx.x & 63;
    int c2 = lane & 15;
    int m  = lane >> 4;
    float ax = 0.f, ay = 0.f;
    bf8 hv0 = *(const bf8*)(h0b + (size_t)dst * NEMB + m * 16);
    bf8 hv1 = *(const bf8*)(h0b + (size_t)dst * NEMB + m * 16 + 8);
    const float2* rt = (const float2*)root1;
#pragma unroll
    for (int k = 0; k < 8; k++) {
        float a = (float)hv0[k];
        float2 w = rt[(size_t)(m * 16 + k) * 16 + c2];
        ax += a * w.x; ay += a * w.y;
    }
#pragma unroll
    for (int k = 0; k < 8; k++) {
        float a = (float)hv1[k];
        float2 w = rt[(size_t)(m * 16 + 8 + k) * 16 + c2];
        ax += a * w.x; ay += a * w.y;
    }
    int s = row_start[dst], e = row_start[dst + 1];
    for (int i = s + m; i < e; i += 4) {
        unsigned v = msg1[(size_t)i * 16 + c2];
        ax += blo(v); ay += bhi(v);
    }
    ax += __shfl_xor(ax, 16); ay += __shfl_xor(ay, 16);
    ax += __shfl_xor(ax, 32); ay += __shfl_xor(ay, 32);
    if (m == 0) {
        float2 bsv = ((const float2*)bias1)[c2];
        __bf16 o0 = (__bf16)fmaxf(ax + bsv.x, 0.f);
        __bf16 o1 = (__bf16)fmaxf(ay + bsv.y, 0.f);
        __bf16* hp = h1b + (size_t)dst * NH1 + 2 * c2;
        hp[0] = o0; hp[1] = o1;
    }
}

__global__ __launch_bounds__(256) void k_agg2(const int* __restrict__ row_start,
                                              const unsigned* __restrict__ msg2,   // bf16x2 words
                                              const __bf16* __restrict__ h1b,
                                              const float* __restrict__ root2,
                                              const float* __restrict__ bias2,
                                              float* __restrict__ out) {
    int dst = blockIdx.x * 4 + (threadIdx.x >> 6);
    int lane = threadIdx.x & 63;
    int c2 = lane & 7;
    int m  = lane >> 3;
    float ax = 0.f, ay = 0.f;
    bf4 hv = *(const bf4*)(h1b + (size_t)dst * NH1 + m * 4);
    const float2* rt = (const float2*)root2;
#pragma unroll
    for (int k = 0; k < 4; k++) {
        float a = (float)hv[k];
        float2 w = rt[(size_t)(m * 4 + k) * 8 + c2];
        ax += a * w.x; ay += a * w.y;
    }
    int s = row_start[dst], e = row_start[dst + 1];
    for (int i = s + m; i < e; i += 8) {
        unsigned v = msg2[(size_t)i * 8 + c2];
        ax += blo(v); ay += bhi(v);
    }
    ax += __shfl_xor(ax, 8);  ay += __shfl_xor(ay, 8);
    ax += __shfl_xor(ax, 16); ay += __shfl_xor(ay, 16);
    ax += __shfl_xor(ax, 32); ay += __shfl_xor(ay, 32);
    if (m == 0) {
        float2 bsv = ((const float2*)bias2)[c2];
        float2 o;
        o.x = fmaxf(ax + bsv.x, 0.f);
        o.y = fmaxf(ay + bsv.y, 0.f);
        ((float2*)out)[(size_t)dst * 8 + c2] = o;
    }
}

// ---------------- launch ----------------
extern "C" void kernel_launch(void* const* d_in, const int* in_sizes, int n_in,
                              void* d_out, int out_size, void* d_ws, size_t ws_size,
                              hipStream_t stream) {
    const float* x      = (const float*)d_in[0];
    const int*   ei     = (const int*)d_in[1];
    const int*   et     = (const int*)d_in[2];
    const float* xnorm  = (const float*)d_in[4];
    const float* embed  = (const float*)d_in[5];
    const float* basis1 = (const float*)d_in[6];
    const float* att1   = (const float*)d_in[7];
    const float* root1  = (const float*)d_in[8];
    const float* bias1  = (const float*)d_in[9];
    const float* basis2 = (const float*)d_in[10];
    const float* att2   = (const float*)d_in[11];
    const float* root2  = (const float*)d_in[12];
    const float* bias2  = (const float*)d_in[13];
    float* out = (float*)d_out;

    char* ws = (char*)d_ws;
    __bf16* embT = (__bf16*)(ws + 0);              //   262,144
    __bf16* W1T  = (__bf16*)(ws + 262144);         //   262,144
    __bf16* W2T  = (__bf16*)(ws + 524288);         //    65,536
    __bf16* h0b  = (__bf16*)(ws + 589824);         // 3,840,000
    __bf16* h1b  = (__bf16*)(ws + 4429824);        // 1,920,000
    int*    deg  = (int*)   (ws + 6349824);        //   120,000
    int*    rs   = (int*)   (ws + 6469824);        //   120,064
    int*    cur  = (int*)   (ws + 6589888);        //   120,000
    int*    epos = (int*)   (ws + 6709888);        // 3,840,000
    __bf16* msg1 = (__bf16*)(ws + 10549888);       // 61,440,000
    __bf16* msg2 = (__bf16*)(ws + 71989888);       // 30,720,000  (end ~102.7 MB)

    hipMemsetAsync(deg, 0, NN * sizeof(int), stream);
    k_prep_hist <<<1152, 256, 0, stream>>>(embed, basis1, att1, basis2, att2, ei,
                                           embT, W1T, W2T, deg);
    k_scan_embed<<<1876, 256, 0, stream>>>(deg, rs, cur, x, xnorm, embT, h0b);
    k_edge1     <<<7500, 256, 0, stream>>>(ei, et, h0b, W1T, cur, epos, msg1);
    k_agg1      <<<7500, 256, 0, stream>>>(rs, (const unsigned*)msg1, h0b, root1, bias1, h1b);
    k_edge2     <<<7500, 256, 0, stream>>>(ei, et, epos, h1b, W2T, msg2);
    k_agg2      <<<7500, 256, 0, stream>>>(rs, (const unsigned*)msg2, h1b, root2, bias2, out);
}

// Round 6
// 331.951 us; speedup vs baseline: 1.3352x; 1.0211x over previous
//
#include <hip/hip_runtime.h>
#include <hip/hip_bf16.h>

#define NN   30000
#define EE   960000
#define IND  2048
#define NEMB 64
#define NH1  32
#define NH2  16
#define NET  64
#define NB   16

#define BM   32          // rows per block (embed GEMM)
#define BK   256         // K chunk
#define NCH  (IND/BK)    // 8 chunks
#define APAD 264         // A LDS row stride (bf16): conflict-optimal

typedef __bf16 bf8 __attribute__((ext_vector_type(8)));
typedef __bf16 bf4 __attribute__((ext_vector_type(4)));
typedef float  f4  __attribute__((ext_vector_type(4)));

#define AS3 __attribute__((address_space(3)))
#define AS1 __attribute__((address_space(1)))

__device__ __forceinline__ void gll16(const void* g, void* l) {
    __builtin_amdgcn_global_load_lds((const AS1 unsigned int*)g,
                                     (AS3 unsigned int*)l, 16, 0, 0);
}

__device__ __forceinline__ bf8 bf8_zero() {
    bf8 z;
#pragma unroll
    for (int i = 0; i < 8; i++) z[i] = (__bf16)0.0f;
    return z;
}
__device__ __forceinline__ float blo(unsigned v) { return __uint_as_float(v << 16); }
__device__ __forceinline__ float bhi(unsigned v) { return __uint_as_float(v & 0xffff0000u); }

// ---------------- prep (embT/W1T/W2T) + hist, grid-split ----------------
__global__ __launch_bounds__(256) void k_prep_hist(const float* __restrict__ embed,
                                                   const float* __restrict__ basis1,
                                                   const float* __restrict__ att1,
                                                   const float* __restrict__ basis2,
                                                   const float* __restrict__ att2,
                                                   const int* __restrict__ ei,
                                                   __bf16* __restrict__ embT,
                                                   __bf16* __restrict__ W1T,
                                                   __bf16* __restrict__ W2T,
                                                   int* __restrict__ deg) {
    int b = blockIdx.x;
    if (b < 512) {
        int idx = b * 256 + threadIdx.x;        // embT[n][k] = embed[k][n]
        int n = idx >> 11, k = idx & 2047;
        embT[idx] = (__bf16)embed[k * NEMB + n];
    } else if (b < 576) {
        int r = b - 512;
        __shared__ float a[NB];
        if (threadIdx.x < NB) a[threadIdx.x] = att1[r * NB + threadIdx.x];
        __syncthreads();
        for (int idx = threadIdx.x; idx < NH1 * NEMB; idx += 256) {
            int o = idx >> 6, i = idx & 63;
            float acc = 0.f;
#pragma unroll
            for (int bb = 0; bb < NB; bb++) acc += a[bb] * basis1[(bb * NEMB + i) * NH1 + o];
            W1T[r * (NH1 * NEMB) + idx] = (__bf16)acc;
        }
    } else if (b < 640) {
        int r = b - 576;
        __shared__ float a[NB];
        if (threadIdx.x < NB) a[threadIdx.x] = att2[r * NB + threadIdx.x];
        __syncthreads();
        for (int idx = threadIdx.x; idx < NH2 * NH1; idx += 256) {
            int o = idx >> 5, i = idx & 31;
            float acc = 0.f;
#pragma unroll
            for (int bb = 0; bb < NB; bb++) acc += a[bb] * basis2[(bb * NH1 + i) * NH2 + o];
            W2T[r * (NH2 * NH1) + idx] = (__bf16)acc;
        }
    } else {
        for (int e = (b - 640) * 256 + threadIdx.x; e < EE; e += 512 * 256)
            atomicAdd(&deg[ei[EE + e]], 1);
    }
}

// ---------------- scan (block 0) + m97-style K-chunked LDS GEMM ----------------
// blocks 1..938: 32 rows x 64 cols, K in 8 chunks of 256.
// A: f32 global -> regs (8 indep float4) -> cvt -> LDS [32][264] bf16 (pad).
// B: embT (L2-hot) -> global_load_lds w16, linear LDS, XOR-swizzled src+read.
// 49.6 KB LDS -> 3 blocks/CU; cross-block overlap hides chunk latency.
__global__ __launch_bounds__(256, 3) void k_scan_embed(const int* __restrict__ deg,
                                                       int* __restrict__ rs,
                                                       int* __restrict__ cur,
                                                       const float* __restrict__ x,
                                                       const float* __restrict__ xnorm,
                                                       const __bf16* __restrict__ embT,
                                                       __bf16* __restrict__ h0b) {
    __shared__ __align__(16) __bf16 As[BM][APAD];     // 16,896 B
    __shared__ __align__(16) __bf16 Bs[64 * BK];      // 32,768 B, linear+swizzled
    if (blockIdx.x == 0) {
        int* lds = (int*)&As[0][0];
        int t = threadIdx.x;
        const int PER = 118;                      // 256*118 = 30208 >= NN
        int i0 = t * PER;
        int s = 0;
        for (int j = 0; j < PER; j++) { int i = i0 + j; if (i < NN) s += deg[i]; }
        lds[t] = s;
        __syncthreads();
        for (int off = 1; off < 256; off <<= 1) {
            int add = (t >= off) ? lds[t - off] : 0;
            __syncthreads();
            lds[t] += add;
            __syncthreads();
        }
        int run = lds[t] - s;
        for (int j = 0; j < PER; j++) {
            int i = i0 + j;
            if (i < NN) { rs[i] = run; cur[i] = run; run += deg[i]; }
        }
        if (t == 0) rs[NN] = EE;
        return;
    }
    int t = threadIdx.x;
    int wv = t >> 6, lane = t & 63;
    int l15 = lane & 15, kg = lane >> 4;
    int rowbase = (blockIdx.x - 1) * BM;
    // A staging geometry: thread -> row t>>3, 32 consecutive floats at (t&7)*32
    int ar = t >> 3, ac = (t & 7) * 32;
    int arow = rowbase + ar;
    const float* xrow = x + (size_t)(arow < NN ? arow : NN - 1) * IND + ac;
    // B staging geometry: wave wv issues rp = wv*8+i, rows 2rp,2rp+1
    int brow_lo = lane >> 5;                 // 0/1 within row-pair
    int bslot = lane & 31;
    // compute-side constants
    int n = wv * 16 + l15;                   // output col = Bs row
    int nswz = (n & 7) << 4;
    const char* bsrow = (const char*)Bs + n * (BK * 2);
    f4 acc0 = (f4)0.0f, acc1 = (f4)0.0f;

    for (int c = 0; c < NCH; c++) {
        // ---- stage A: 8 independent float4 loads, cvt, 4x ds_write_b128 ----
        const float* ap = xrow + c * BK;
        float4 f0 = *(const float4*)(ap + 0);
        float4 f1 = *(const float4*)(ap + 4);
        float4 f2 = *(const float4*)(ap + 8);
        float4 f3 = *(const float4*)(ap + 12);
        float4 f4_ = *(const float4*)(ap + 16);
        float4 f5 = *(const float4*)(ap + 20);
        float4 f6 = *(const float4*)(ap + 24);
        float4 f7 = *(const float4*)(ap + 28);
        // ---- stage B: 8 global_load_lds per wave (pre-swizzled source) ----
#pragma unroll
        for (int i = 0; i < 8; i++) {
            int rp = wv * 8 + i;
            int row = rp * 2 + brow_lo;
            int swz = (bslot * 16) ^ ((row & 7) << 4);
            const char* g = (const char*)embT + (size_t)row * (IND * 2) + c * (BK * 2) + swz;
            gll16(g, (char*)Bs + rp * 1024);
        }
        bf8 o0, o1, o2, o3;
        o0[0]=(__bf16)f0.x; o0[1]=(__bf16)f0.y; o0[2]=(__bf16)f0.z; o0[3]=(__bf16)f0.w;
        o0[4]=(__bf16)f1.x; o0[5]=(__bf16)f1.y; o0[6]=(__bf16)f1.z; o0[7]=(__bf16)f1.w;
        o1[0]=(__bf16)f2.x; o1[1]=(__bf16)f2.y; o1[2]=(__bf16)f2.z; o1[3]=(__bf16)f2.w;
        o1[4]=(__bf16)f3.x; o1[5]=(__bf16)f3.y; o1[6]=(__bf16)f3.z; o1[7]=(__bf16)f3.w;
        o2[0]=(__bf16)f4_.x;o2[1]=(__bf16)f4_.y;o2[2]=(__bf16)f4_.z;o2[3]=(__bf16)f4_.w;
        o2[4]=(__bf16)f5.x; o2[5]=(__bf16)f5.y; o2[6]=(__bf16)f5.z; o2[7]=(__bf16)f5.w;
        o3[0]=(__bf16)f6.x; o3[1]=(__bf16)f6.y; o3[2]=(__bf16)f6.z; o3[3]=(__bf16)f6.w;
        o3[4]=(__bf16)f7.x; o3[5]=(__bf16)f7.y; o3[6]=(__bf16)f7.z; o3[7]=(__bf16)f7.w;
        *(bf8*)&As[ar][ac + 0]  = o0;
        *(bf8*)&As[ar][ac + 8]  = o1;
        *(bf8*)&As[ar][ac + 16] = o2;
        *(bf8*)&As[ar][ac + 24] = o3;
        __syncthreads();
        // ---- compute: 16 MFMAs per wave ----
#pragma unroll
        for (int kk = 0; kk < BK / 32; kk++) {
            bf8 a0 = *(const bf8*)&As[l15][kk * 32 + kg * 8];
            bf8 a1 = *(const bf8*)&As[l15 + 16][kk * 32 + kg * 8];
            bf8 b  = *(const bf8*)(bsrow + (((kk * 64) + (kg * 16)) ^ nswz));
            acc0 = __builtin_amdgcn_mfma_f32_16x16x32_bf16(a0, b, acc0, 0, 0, 0);
            acc1 = __builtin_amdgcn_mfma_f32_16x16x32_bf16(a1, b, acc1, 0, 0, 0);
        }
        __syncthreads();
    }
#pragma unroll
    for (int j = 0; j < 4; j++) {
        int r0 = rowbase + kg * 4 + j;
        int r1 = r0 + 16;
        if (r0 < NN) h0b[(size_t)r0 * NEMB + n] = (__bf16)(acc0[j] / xnorm[r0]);
        if (r1 < NN) h0b[(size_t)r1 * NEMB + n] = (__bf16)(acc1[j] / xnorm[r1]);
    }
}

// ---------------- edge layer 1: MFMA batch + fused slot-atomic + LDS-transposed store ----------------
__global__ __launch_bounds__(256) void k_edge1(const int* __restrict__ ei,
                                               const int* __restrict__ et,
                                               const __bf16* __restrict__ h0b,
                                               const __bf16* __restrict__ W1T,
                                               int* __restrict__ cur,
                                               int* __restrict__ epos,
                                               __bf16* __restrict__ msg1) {
    __shared__ __bf16 lt[4][16][32];
    int wave = threadIdx.x >> 6, lane = threadIdx.x & 63;
    int l15 = lane & 15, kg = lane >> 4;
    int wid = blockIdx.x * 4 + wave;             // 30000 waves, 32 edges each
    int row = lane >> 2, q = lane & 3;
#pragma unroll
    for (int b = 0; b < 2; b++) {
        int er = wid * 32 + b * 16 + l15;
        int my_et  = et[er];
        int my_src = ei[er];
        const __bf16* hp = h0b + (size_t)my_src * NEMB + kg * 8;
        bf8 a0 = *(const bf8*)hp;
        bf8 a1 = *(const bf8*)(hp + 32);
        bf8 zero = bf8_zero();
        f4 c0 = (f4)0.0f, c1 = (f4)0.0f;
        int pos = 0;
        while (pos < 16) {
            int r = __shfl(my_et, pos);
            unsigned long long bl = __ballot(my_et == r);
            unsigned m16 = (unsigned)(bl & 0xFFFFull);
            int run = __builtin_ctz(~(m16 >> pos));
            int end = pos + run;
            const __bf16* wb = W1T + (size_t)r * (NH1 * NEMB) + (size_t)l15 * NEMB + kg * 8;
            bf8 b00 = *(const bf8*)(wb);
            bf8 b01 = *(const bf8*)(wb + 32);
            bf8 b10 = *(const bf8*)(wb + 16 * NEMB);
            bf8 b11 = *(const bf8*)(wb + 16 * NEMB + 32);
            bool use = (l15 >= pos) && (l15 < end);
            bf8 ua0 = use ? a0 : zero;
            bf8 ua1 = use ? a1 : zero;
            c0 = __builtin_amdgcn_mfma_f32_16x16x32_bf16(ua0, b00, c0, 0, 0, 0);
            c0 = __builtin_amdgcn_mfma_f32_16x16x32_bf16(ua1, b01, c0, 0, 0, 0);
            c1 = __builtin_amdgcn_mfma_f32_16x16x32_bf16(ua0, b10, c1, 0, 0, 0);
            c1 = __builtin_amdgcn_mfma_f32_16x16x32_bf16(ua1, b11, c1, 0, 0, 0);
            pos = end;
        }
        int slotv = 0;
        if (kg == 0) {
            slotv = atomicAdd(&cur[ei[EE + er]], 1);
            epos[er] = slotv;
        }
#pragma unroll
        for (int j = 0; j < 4; j++) {
            lt[wave][kg * 4 + j][l15]      = (__bf16)c0[j];
            lt[wave][kg * 4 + j][16 + l15] = (__bf16)c1[j];
        }
        int slot = __shfl(slotv, row);           // lane `row` (<16) holds edge row's slot
        bf8 v = *(const bf8*)&lt[wave][row][q * 8];
        *(bf8*)(msg1 + (size_t)slot * NH1 + q * 8) = v;
    }
}

// ---------------- edge layer 2 ----------------
__global__ __launch_bounds__(256) void k_edge2(const int* __restrict__ ei,
                                               const int* __restrict__ et,
                                               const int* __restrict__ epos,
                                               const __bf16* __restrict__ h1b,
                                               const __bf16* __restrict__ W2T,
                                               __bf16* __restrict__ msg2) {
    __shared__ __bf16 lt[4][16][16];
    int wave = threadIdx.x >> 6, lane = threadIdx.x & 63;
    int l15 = lane & 15, kg = lane >> 4;
    int wid = blockIdx.x * 4 + wave;
    int row = lane >> 2, q = lane & 3;
#pragma unroll
    for (int b = 0; b < 2; b++) {
        int er = wid * 32 + b * 16 + l15;
        int my_et  = et[er];
        int my_src = ei[er];
        int slotv  = epos[er];
        bf8 a = *(const bf8*)(h1b + (size_t)my_src * NH1 + kg * 8);
        bf8 zero = bf8_zero();
        f4 c = (f4)0.0f;
        int pos = 0;
        while (pos < 16) {
            int r = __shfl(my_et, pos);
            unsigned long long bl = __ballot(my_et == r);
            unsigned m16 = (unsigned)(bl & 0xFFFFull);
            int run = __builtin_ctz(~(m16 >> pos));
            int end = pos + run;
            bf8 bb = *(const bf8*)(W2T + (size_t)r * (NH2 * NH1) + (size_t)l15 * NH1 + kg * 8);
            bool use = (l15 >= pos) && (l15 < end);
            c = __builtin_amdgcn_mfma_f32_16x16x32_bf16(use ? a : zero, bb, c, 0, 0, 0);
            pos = end;
        }
#pragma unroll
        for (int j = 0; j < 4; j++) lt[wave][kg * 4 + j][l15] = (__bf16)c[j];
        int slot = __shfl(slotv, row);
        bf4 v = *(const bf4*)&lt[wave][row][q * 4];
        *(bf4*)(msg2 + (size_t)slot * NH2 + q * 4) = v;
    }
}

// ---------------- per-dst aggregation (stream) + root + bias + relu ----------------
__global__ __launch_bounds__(256) void k_agg1(const int* __restrict__ row_start,
                                              const unsigned* __restrict__ msg1,   // bf16x2 words
                                              const __bf16* __restrict__ h0b,
                                              const float* __restrict__ root1,
                                              const float* __restrict__ bias1,
                                              __bf16* __restrict__ h1b) {
    int dst = blockIdx.x * 4 + (threadIdx.x >> 6);
    int lane = threadIdx.x & 63;
    int c2 = lane & 15;
    int m  = lane >> 4;
    float ax = 0.f, ay = 0.f;
    bf8 hv0 = *(const bf8*)(h0b + (size_t)dst * NEMB + m * 16);
    bf8 hv1 = *(const bf8*)(h0b + (size_t)dst * NEMB + m * 16 + 8);
    const float2* rt = (const float2*)root1;
#pragma unroll
    for (int k = 0; k < 8; k++) {
        float a = (float)hv0[k];
        float2 w = rt[(size_t)(m * 16 + k) * 16 + c2];
        ax += a * w.x; ay += a * w.y;
    }
#pragma unroll
    for (int k = 0; k < 8; k++) {
        float a = (float)hv1[k];
        float2 w = rt[(size_t)(m * 16 + 8 + k) * 16 + c2];
        ax += a * w.x; ay += a * w.y;
    }
    int s = row_start[dst], e = row_start[dst + 1];
    for (int i = s + m; i < e; i += 4) {
        unsigned v = msg1[(size_t)i * 16 + c2];
        ax += blo(v); ay += bhi(v);
    }
    ax += __shfl_xor(ax, 16); ay += __shfl_xor(ay, 16);
    ax += __shfl_xor(ax, 32); ay += __shfl_xor(ay, 32);
    if (m == 0) {
        float2 bsv = ((const float2*)bias1)[c2];
        __bf16 o0 = (__bf16)fmaxf(ax + bsv.x, 0.f);
        __bf16 o1 = (__bf16)fmaxf(ay + bsv.y, 0.f);
        __bf16* hp = h1b + (size_t)dst * NH1 + 2 * c2;
        hp[0] = o0; hp[1] = o1;
    }
}

__global__ __launch_bounds__(256) void k_agg2(const int* __restrict__ row_start,
                                              const unsigned* __restrict__ msg2,   // bf16x2 words
                                              const __bf16* __restrict__ h1b,
                                              const float* __restrict__ root2,
                                              const float* __restrict__ bias2,
                                              float* __restrict__ out) {
    int dst = blockIdx.x * 4 + (threadIdx.x >> 6);
    int lane = threadIdx.x & 63;
    int c2 = lane & 7;
    int m  = lane >> 3;
    float ax = 0.f, ay = 0.f;
    bf4 hv = *(const bf4*)(h1b + (size_t)dst * NH1 + m * 4);
    const float2* rt = (const float2*)root2;
#pragma unroll
    for (int k = 0; k < 4; k++) {
        float a = (float)hv[k];
        float2 w = rt[(size_t)(m * 4 + k) * 8 + c2];
        ax += a * w.x; ay += a * w.y;
    }
    int s = row_start[dst], e = row_start[dst + 1];
    for (int i = s + m; i < e; i += 8) {
        unsigned v = msg2[(size_t)i * 8 + c2];
        ax += blo(v); ay += bhi(v);
    }
    ax += __shfl_xor(ax, 8);  ay += __shfl_xor(ay, 8);
    ax += __shfl_xor(ax, 16); ay += __shfl_xor(ay, 16);
    ax += __shfl_xor(ax, 32); ay += __shfl_xor(ay, 32);
    if (m == 0) {
        float2 bsv = ((const float2*)bias2)[c2];
        float2 o;
        o.x = fmaxf(ax + bsv.x, 0.f);
        o.y = fmaxf(ay + bsv.y, 0.f);
        ((float2*)out)[(size_t)dst * 8 + c2] = o;
    }
}

// ---------------- launch ----------------
extern "C" void kernel_launch(void* const* d_in, const int* in_sizes, int n_in,
                              void* d_out, int out_size, void* d_ws, size_t ws_size,
                              hipStream_t stream) {
    const float* x      = (const float*)d_in[0];
    const int*   ei     = (const int*)d_in[1];
    const int*   et     = (const int*)d_in[2];
    const float* xnorm  = (const float*)d_in[4];
    const float* embed  = (const float*)d_in[5];
    const float* basis1 = (const float*)d_in[6];
    const float* att1   = (const float*)d_in[7];
    const float* root1  = (const float*)d_in[8];
    const float* bias1  = (const float*)d_in[9];
    const float* basis2 = (const float*)d_in[10];
    const float* att2   = (const float*)d_in[11];
    const float* root2  = (const float*)d_in[12];
    const float* bias2  = (const float*)d_in[13];
    float* out = (float*)d_out;

    char* ws = (char*)d_ws;
    __bf16* embT = (__bf16*)(ws + 0);              //   262,144
    __bf16* W1T  = (__bf16*)(ws + 262144);         //   262,144
    __bf16* W2T  = (__bf16*)(ws + 524288);         //    65,536
    __bf16* h0b  = (__bf16*)(ws + 589824);         // 3,840,000
    __bf16* h1b  = (__bf16*)(ws + 4429824);        // 1,920,000
    int*    deg  = (int*)   (ws + 6349824);        //   120,000
    int*    rs   = (int*)   (ws + 6469824);        //   120,064
    int*    cur  = (int*)   (ws + 6589888);        //   120,000
    int*    epos = (int*)   (ws + 6709888);        // 3,840,000
    __bf16* msg1 = (__bf16*)(ws + 10549888);       // 61,440,000
    __bf16* msg2 = (__bf16*)(ws + 71989888);       // 30,720,000  (end ~102.7 MB)

    hipMemsetAsync(deg, 0, NN * sizeof(int), stream);
    k_prep_hist <<<1152, 256, 0, stream>>>(embed, basis1, att1, basis2, att2, ei,
                                           embT, W1T, W2T, deg);
    k_scan_embed<<<939,  256, 0, stream>>>(deg, rs, cur, x, xnorm, embT, h0b);
    k_edge1     <<<7500, 256, 0, stream>>>(ei, et, h0b, W1T, cur, epos, msg1);
    k_agg1      <<<7500, 256, 0, stream>>>(rs, (const unsigned*)msg1, h0b, root1, bias1, h1b);
    k_edge2     <<<7500, 256, 0, stream>>>(ei, et, epos, h1b, W2T, msg2);
    k_agg2      <<<7500, 256, 0, stream>>>(rs, (const unsigned*)msg2, h1b, root2, bias2, out);
}

// Round 8
// 293.708 us; speedup vs baseline: 1.5091x; 1.1302x over previous
//
#include <hip/hip_runtime.h>
#include <hip/hip_bf16.h>

#define NN   30000
#define EE   960000
#define IND  2048
#define NEMB 64
#define NH1  32
#define NH2  16
#define NET  64
#define NB   16

typedef __bf16 bf8 __attribute__((ext_vector_type(8)));
typedef __bf16 bf4 __attribute__((ext_vector_type(4)));
typedef float  f4  __attribute__((ext_vector_type(4)));

#define AS3 __attribute__((address_space(3)))
#define AS1 __attribute__((address_space(1)))

__device__ __forceinline__ void gll16(const void* g, void* l) {
    __builtin_amdgcn_global_load_lds((const AS1 unsigned int*)g,
                                     (AS3 unsigned int*)l, 16, 0, 0);
}

__device__ __forceinline__ bf8 bf8_zero() {
    bf8 z;
#pragma unroll
    for (int i = 0; i < 8; i++) z[i] = (__bf16)0.0f;
    return z;
}
__device__ __forceinline__ float blo(unsigned v) { return __uint_as_float(v << 16); }
__device__ __forceinline__ float bhi(unsigned v) { return __uint_as_float(v & 0xffff0000u); }

// ---------------- prep (embT/W1T/W2T) + hist, grid-split ----------------
__global__ __launch_bounds__(256) void k_prep_hist(const float* __restrict__ embed,
                                                   const float* __restrict__ basis1,
                                                   const float* __restrict__ att1,
                                                   const float* __restrict__ basis2,
                                                   const float* __restrict__ att2,
                                                   const int* __restrict__ ei,
                                                   __bf16* __restrict__ embT,
                                                   __bf16* __restrict__ W1T,
                                                   __bf16* __restrict__ W2T,
                                                   int* __restrict__ deg) {
    int b = blockIdx.x;
    if (b < 512) {
        int idx = b * 256 + threadIdx.x;        // embT[n][k] = embed[k][n]
        int n = idx >> 11, k = idx & 2047;
        embT[idx] = (__bf16)embed[k * NEMB + n];
    } else if (b < 576) {
        int r = b - 512;
        __shared__ float a[NB];
        if (threadIdx.x < NB) a[threadIdx.x] = att1[r * NB + threadIdx.x];
        __syncthreads();
        for (int idx = threadIdx.x; idx < NH1 * NEMB; idx += 256) {
            int o = idx >> 6, i = idx & 63;
            float acc = 0.f;
#pragma unroll
            for (int bb = 0; bb < NB; bb++) acc += a[bb] * basis1[(bb * NEMB + i) * NH1 + o];
            W1T[r * (NH1 * NEMB) + idx] = (__bf16)acc;
        }
    } else if (b < 640) {
        int r = b - 576;
        __shared__ float a[NB];
        if (threadIdx.x < NB) a[threadIdx.x] = att2[r * NB + threadIdx.x];
        __syncthreads();
        for (int idx = threadIdx.x; idx < NH2 * NH1; idx += 256) {
            int o = idx >> 5, i = idx & 31;
            float acc = 0.f;
#pragma unroll
            for (int bb = 0; bb < NB; bb++) acc += a[bb] * basis2[(bb * NH1 + i) * NH2 + o];
            W2T[r * (NH2 * NH1) + idx] = (__bf16)acc;
        }
    } else {
        for (int e = (b - 640) * 256 + threadIdx.x; e < EE; e += 512 * 256)
            atomicAdd(&deg[ei[EE + e]], 1);
    }
}

// ---------------- standalone scan: 1024 threads, values in regs ----------------
__global__ __launch_bounds__(1024) void k_scan(const int* __restrict__ deg,
                                               int* __restrict__ rs,
                                               int* __restrict__ cur) {
    const int PER = 30;                        // 1024*30 = 30720 >= NN
    int t = threadIdx.x;
    int lane = t & 63, wv = t >> 6;
    int i0 = t * PER;
    int v[PER];
    int s = 0;
#pragma unroll
    for (int j = 0; j < PER; j++) {
        int i = i0 + j;
        v[j] = (i < NN) ? deg[i] : 0;
        s += v[j];
    }
    // wave-inclusive scan of s
    int incl = s;
#pragma unroll
    for (int off = 1; off < 64; off <<= 1) {
        int u = __shfl_up(incl, off);
        if (lane >= off) incl += u;
    }
    __shared__ int wsum[16], wbase[16];
    if (lane == 63) wsum[wv] = incl;
    __syncthreads();
    if (t == 0) {
        int acc = 0;
#pragma unroll
        for (int w = 0; w < 16; w++) { wbase[w] = acc; acc += wsum[w]; }
    }
    __syncthreads();
    int run = wbase[wv] + incl - s;            // exclusive prefix for this thread
#pragma unroll
    for (int j = 0; j < PER; j++) {
        int i = i0 + j;
        if (i < NN) { rs[i] = run; cur[i] = run; run += v[j]; }
    }
    if (t == 0) rs[NN] = EE;
}

// ---------------- embed GEMM: pure global_load_lds staging (zero staging VGPRs) ----
// 32 rows x 64 cols per block, K in 16 chunks of 128.
// A: f32 x -> LDS [32][128] f32 (16KB), XOR-swizzled src + read, cvt at use.
// B: embT bf16 -> LDS [64][128] bf16 (16KB), same scheme. 32KB -> 4-5 blocks/CU.
__global__ __launch_bounds__(256) void k_gemm(const float* __restrict__ x,
                                              const float* __restrict__ xnorm,
                                              const __bf16* __restrict__ embT,
                                              __bf16* __restrict__ h0b) {
    __shared__ __align__(16) float  As[32 * 128];    // 16,384 B
    __shared__ __align__(16) __bf16 Bs[64 * 128];    // 16,384 B
    int t = threadIdx.x;
    int wv = t >> 6, lane = t & 63;
    int l15 = lane & 15, kg = lane >> 4;
    int rowbase = blockIdx.x * 32;
    int half = lane >> 5;                 // A: row within 512B pair
    int bslot = lane & 31;                // A: 16B slot within 512B row
    int q16 = lane >> 4;                  // B: row within 1KB quad
    int slot16 = lane & 15;               // B: 16B slot within 256B row
    int n = wv * 16 + l15;                // output col = Bs row
    int nswz = (n & 7) << 4;
    int aswz = (l15 & 7) << 4;            // rows l15 and l15+16 share (row&7)
    const char* bsrow  = (const char*)Bs + n * 256;
    const char* asrow0 = (const char*)As + l15 * 512;
    const char* asrow1 = (const char*)As + (l15 + 16) * 512;
    f4 acc0 = (f4)0.0f, acc1 = (f4)0.0f;

    for (int c = 0; c < 16; c++) {
        // ---- stage A: 4 gll per wave (2 rows x 512B each) ----
#pragma unroll
        for (int i = 0; i < 4; i++) {
            int rp = wv * 4 + i;
            int row = rp * 2 + half;
            int grow = rowbase + row;
            if (grow >= NN) grow = NN - 1;
            const char* g = (const char*)x + (size_t)grow * (IND * 4) + c * 512
                          + ((bslot * 16) ^ ((row & 7) << 4));
            gll16(g, (char*)As + rp * 1024);
        }
        // ---- stage B: 4 gll per wave (4 rows x 256B each) ----
#pragma unroll
        for (int i = 0; i < 4; i++) {
            int rp = wv * 4 + i;
            int row = rp * 4 + q16;
            const char* g = (const char*)embT + (size_t)row * (IND * 2) + c * 256
                          + ((slot16 * 16) ^ ((row & 7) << 4));
            gll16(g, (char*)Bs + rp * 1024);
        }
        __syncthreads();
        // ---- compute: 8 MFMAs per wave ----
#pragma unroll
        for (int kk = 0; kk < 4; kk++) {
            int aoff = ((kk * 128 + kg * 32) ^ aswz);
            float4 lo0 = *(const float4*)(asrow0 + aoff);
            float4 hi0 = *(const float4*)(asrow0 + (aoff ^ 16));
            float4 lo1 = *(const float4*)(asrow1 + aoff);
            float4 hi1 = *(const float4*)(asrow1 + (aoff ^ 16));
            bf8 b = *(const bf8*)(bsrow + ((kk * 64 + kg * 16) ^ nswz));
            bf8 a0, a1;
            a0[0]=(__bf16)lo0.x; a0[1]=(__bf16)lo0.y; a0[2]=(__bf16)lo0.z; a0[3]=(__bf16)lo0.w;
            a0[4]=(__bf16)hi0.x; a0[5]=(__bf16)hi0.y; a0[6]=(__bf16)hi0.z; a0[7]=(__bf16)hi0.w;
            a1[0]=(__bf16)lo1.x; a1[1]=(__bf16)lo1.y; a1[2]=(__bf16)lo1.z; a1[3]=(__bf16)lo1.w;
            a1[4]=(__bf16)hi1.x; a1[5]=(__bf16)hi1.y; a1[6]=(__bf16)hi1.z; a1[7]=(__bf16)hi1.w;
            acc0 = __builtin_amdgcn_mfma_f32_16x16x32_bf16(a0, b, acc0, 0, 0, 0);
            acc1 = __builtin_amdgcn_mfma_f32_16x16x32_bf16(a1, b, acc1, 0, 0, 0);
        }
        __syncthreads();
    }
#pragma unroll
    for (int j = 0; j < 4; j++) {
        int r0 = rowbase + kg * 4 + j;
        int r1 = r0 + 16;
        if (r0 < NN) h0b[(size_t)r0 * NEMB + n] = (__bf16)(acc0[j] / xnorm[r0]);
        if (r1 < NN) h0b[(size_t)r1 * NEMB + n] = (__bf16)(acc1[j] / xnorm[r1]);
    }
}

// ---------------- edge layer 1: MFMA batch + fused slot-atomic + LDS-transposed store ----------------
__global__ __launch_bounds__(256) void k_edge1(const int* __restrict__ ei,
                                               const int* __restrict__ et,
                                               const __bf16* __restrict__ h0b,
                                               const __bf16* __restrict__ W1T,
                                               int* __restrict__ cur,
                                               int* __restrict__ epos,
                                               __bf16* __restrict__ msg1) {
    __shared__ __bf16 lt[4][16][32];
    int wave = threadIdx.x >> 6, lane = threadIdx.x & 63;
    int l15 = lane & 15, kg = lane >> 4;
    int wid = blockIdx.x * 4 + wave;             // 30000 waves, 32 edges each
    int row = lane >> 2, q = lane & 3;
#pragma unroll
    for (int b = 0; b < 2; b++) {
        int er = wid * 32 + b * 16 + l15;
        int my_et  = et[er];
        int my_src = ei[er];
        const __bf16* hp = h0b + (size_t)my_src * NEMB + kg * 8;
        bf8 a0 = *(const bf8*)hp;
        bf8 a1 = *(const bf8*)(hp + 32);
        bf8 zero = bf8_zero();
        f4 c0 = (f4)0.0f, c1 = (f4)0.0f;
        int pos = 0;
        while (pos < 16) {
            int r = __shfl(my_et, pos);
            unsigned long long bl = __ballot(my_et == r);
            unsigned m16 = (unsigned)(bl & 0xFFFFull);
            int run = __builtin_ctz(~(m16 >> pos));
            int end = pos + run;
            const __bf16* wb = W1T + (size_t)r * (NH1 * NEMB) + (size_t)l15 * NEMB + kg * 8;
            bf8 b00 = *(const bf8*)(wb);
            bf8 b01 = *(const bf8*)(wb + 32);
            bf8 b10 = *(const bf8*)(wb + 16 * NEMB);
            bf8 b11 = *(const bf8*)(wb + 16 * NEMB + 32);
            bool use = (l15 >= pos) && (l15 < end);
            bf8 ua0 = use ? a0 : zero;
            bf8 ua1 = use ? a1 : zero;
            c0 = __builtin_amdgcn_mfma_f32_16x16x32_bf16(ua0, b00, c0, 0, 0, 0);
            c0 = __builtin_amdgcn_mfma_f32_16x16x32_bf16(ua1, b01, c0, 0, 0, 0);
            c1 = __builtin_amdgcn_mfma_f32_16x16x32_bf16(ua0, b10, c1, 0, 0, 0);
            c1 = __builtin_amdgcn_mfma_f32_16x16x32_bf16(ua1, b11, c1, 0, 0, 0);
            pos = end;
        }
        int slotv = 0;
        if (kg == 0) {
            slotv = atomicAdd(&cur[ei[EE + er]], 1);
            epos[er] = slotv;
        }
#pragma unroll
        for (int j = 0; j < 4; j++) {
            lt[wave][kg * 4 + j][l15]      = (__bf16)c0[j];
            lt[wave][kg * 4 + j][16 + l15] = (__bf16)c1[j];
        }
        int slot = __shfl(slotv, row);           // lane `row` (<16) holds edge row's slot
        bf8 v = *(const bf8*)&lt[wave][row][q * 8];
        *(bf8*)(msg1 + (size_t)slot * NH1 + q * 8) = v;
    }
}

// ---------------- edge layer 2 ----------------
__global__ __launch_bounds__(256) void k_edge2(const int* __restrict__ ei,
                                               const int* __restrict__ et,
                                               const int* __restrict__ epos,
                                               const __bf16* __restrict__ h1b,
                                               const __bf16* __restrict__ W2T,
                                               __bf16* __restrict__ msg2) {
    __shared__ __bf16 lt[4][16][16];
    int wave = threadIdx.x >> 6, lane = threadIdx.x & 63;
    int l15 = lane & 15, kg = lane >> 4;
    int wid = blockIdx.x * 4 + wave;
    int row = lane >> 2, q = lane & 3;
#pragma unroll
    for (int b = 0; b < 2; b++) {
        int er = wid * 32 + b * 16 + l15;
        int my_et  = et[er];
        int my_src = ei[er];
        int slotv  = epos[er];
        bf8 a = *(const bf8*)(h1b + (size_t)my_src * NH1 + kg * 8);
        bf8 zero = bf8_zero();
        f4 c = (f4)0.0f;
        int pos = 0;
        while (pos < 16) {
            int r = __shfl(my_et, pos);
            unsigned long long bl = __ballot(my_et == r);
            unsigned m16 = (unsigned)(bl & 0xFFFFull);
            int run = __builtin_ctz(~(m16 >> pos));
            int end = pos + run;
            bf8 bb = *(const bf8*)(W2T + (size_t)r * (NH2 * NH1) + (size_t)l15 * NH1 + kg * 8);
            bool use = (l15 >= pos) && (l15 < end);
            c = __builtin_amdgcn_mfma_f32_16x16x32_bf16(use ? a : zero, bb, c, 0, 0, 0);
            pos = end;
        }
#pragma unroll
        for (int j = 0; j < 4; j++) lt[wave][kg * 4 + j][l15] = (__bf16)c[j];
        int slot = __shfl(slotv, row);
        bf4 v = *(const bf4*)&lt[wave][row][q * 4];
        *(bf4*)(msg2 + (size_t)slot * NH2 + q * 4) = v;
    }
}

// ---------------- per-dst aggregation (stream) + root + bias + relu ----------------
__global__ __launch_bounds__(256) void k_agg1(const int* __restrict__ row_start,
                                              const unsigned* __restrict__ msg1,   // bf16x2 words
                                              const __bf16* __restrict__ h0b,
                                              const float* __restrict__ root1,
                                              const float* __restrict__ bias1,
                                              __bf16* __restrict__ h1b) {
    int dst = blockIdx.x * 4 + (threadIdx.x >> 6);
    int lane = threadIdx.x & 63;
    int c2 = lane & 15;
    int m  = lane >> 4;
    float ax = 0.f, ay = 0.f;
    bf8 hv0 = *(const bf8*)(h0b + (size_t)dst * NEMB + m * 16);
    bf8 hv1 = *(const bf8*)(h0b + (size_t)dst * NEMB + m * 16 + 8);
    const float2* rt = (const float2*)root1;
#pragma unroll
    for (int k = 0; k < 8; k++) {
        float a = (float)hv0[k];
        float2 w = rt[(size_t)(m * 16 + k) * 16 + c2];
        ax += a * w.x; ay += a * w.y;
    }
#pragma unroll
    for (int k = 0; k < 8; k++) {
        float a = (float)hv1[k];
        float2 w = rt[(size_t)(m * 16 + 8 + k) * 16 + c2];
        ax += a * w.x; ay += a * w.y;
    }
    int s = row_start[dst], e = row_start[dst + 1];
    for (int i = s + m; i < e; i += 4) {
        unsigned v = msg1[(size_t)i * 16 + c2];
        ax += blo(v); ay += bhi(v);
    }
    ax += __shfl_xor(ax, 16); ay += __shfl_xor(ay, 16);
    ax += __shfl_xor(ax, 32); ay += __shfl_xor(ay, 32);
    if (m == 0) {
        float2 bsv = ((const float2*)bias1)[c2];
        __bf16 o0 = (__bf16)fmaxf(ax + bsv.x, 0.f);
        __bf16 o1 = (__bf16)fmaxf(ay + bsv.y, 0.f);
        __bf16* hp = h1b + (size_t)dst * NH1 + 2 * c2;
        hp[0] = o0; hp[1] = o1;
    }
}

__global__ __launch_bounds__(256) void k_agg2(const int* __restrict__ row_start,
                                              const unsigned* __restrict__ msg2,   // bf16x2 words
                                              const __bf16* __restrict__ h1b,
                                              const float* __restrict__ root2,
                                              const float* __restrict__ bias2,
                                              float* __restrict__ out) {
    int dst = blockIdx.x * 4 + (threadIdx.x >> 6);
    int lane = threadIdx.x & 63;
    int c2 = lane & 7;
    int m  = lane >> 3;
    float ax = 0.f, ay = 0.f;
    bf4 hv = *(const bf4*)(h1b + (size_t)dst * NH1 + m * 4);
    const float2* rt = (const float2*)root2;
#pragma unroll
    for (int k = 0; k < 4; k++) {
        float a = (float)hv[k];
        float2 w = rt[(size_t)(m * 4 + k) * 8 + c2];
        ax += a * w.x; ay += a * w.y;
    }
    int s = row_start[dst], e = row_start[dst + 1];
    for (int i = s + m; i < e; i += 8) {
        unsigned v = msg2[(size_t)i * 8 + c2];
        ax += blo(v); ay += bhi(v);
    }
    ax += __shfl_xor(ax, 8);  ay += __shfl_xor(ay, 8);
    ax += __shfl_xor(ax, 16); ay += __shfl_xor(ay, 16);
    ax += __shfl_xor(ax, 32); ay += __shfl_xor(ay, 32);
    if (m == 0) {
        float2 bsv = ((const float2*)bias2)[c2];
        float2 o;
        o.x = fmaxf(ax + bsv.x, 0.f);
        o.y = fmaxf(ay + bsv.y, 0.f);
        ((float2*)out)[(size_t)dst * 8 + c2] = o;
    }
}

// ---------------- launch ----------------
extern "C" void kernel_launch(void* const* d_in, const int* in_sizes, int n_in,
                              void* d_out, int out_size, void* d_ws, size_t ws_size,
                              hipStream_t stream) {
    const float* x      = (const float*)d_in[0];
    const int*   ei     = (const int*)d_in[1];
    const int*   et     = (const int*)d_in[2];
    const float* xnorm  = (const float*)d_in[4];
    const float* embed  = (const float*)d_in[5];
    const float* basis1 = (const float*)d_in[6];
    const float* att1   = (const float*)d_in[7];
    const float* root1  = (const float*)d_in[8];
    const float* bias1  = (const float*)d_in[9];
    const float* basis2 = (const float*)d_in[10];
    const float* att2   = (const float*)d_in[11];
    const float* root2  = (const float*)d_in[12];
    const float* bias2  = (const float*)d_in[13];
    float* out = (float*)d_out;

    char* ws = (char*)d_ws;
    __bf16* embT = (__bf16*)(ws + 0);              //   262,144
    __bf16* W1T  = (__bf16*)(ws + 262144);         //   262,144
    __bf16* W2T  = (__bf16*)(ws + 524288);         //    65,536
    __bf16* h0b  = (__bf16*)(ws + 589824);         // 3,840,000
    __bf16* h1b  = (__bf16*)(ws + 4429824);        // 1,920,000
    int*    deg  = (int*)   (ws + 6349824);        //   120,000
    int*    rs   = (int*)   (ws + 6469824);        //   120,064
    int*    cur  = (int*)   (ws + 6589888);        //   120,000
    int*    epos = (int*)   (ws + 6709888);        // 3,840,000
    __bf16* msg1 = (__bf16*)(ws + 10549888);       // 61,440,000
    __bf16* msg2 = (__bf16*)(ws + 71989888);       // 30,720,000  (end ~102.7 MB)

    hipMemsetAsync(deg, 0, NN * sizeof(int), stream);
    k_prep_hist<<<1152, 256,  0, stream>>>(embed, basis1, att1, basis2, att2, ei,
                                           embT, W1T, W2T, deg);
    k_scan     <<<1,    1024, 0, stream>>>(deg, rs, cur);
    k_gemm     <<<938,  256,  0, stream>>>(x, xnorm, embT, h0b);
    k_edge1    <<<7500, 256,  0, stream>>>(ei, et, h0b, W1T, cur, epos, msg1);
    k_agg1     <<<7500, 256,  0, stream>>>(rs, (const unsigned*)msg1, h0b, root1, bias1, h1b);
    k_edge2    <<<7500, 256,  0, stream>>>(ei, et, epos, h1b, W2T, msg2);
    k_agg2     <<<7500, 256,  0, stream>>>(rs, (const unsigned*)msg2, h1b, root2, bias2, out);
}

// Round 9
// 289.059 us; speedup vs baseline: 1.5333x; 1.0161x over previous
//
#include <hip/hip_runtime.h>
#include <hip/hip_bf16.h>

#define NN   30000
#define EE   960000
#define IND  2048
#define NEMB 64
#define NH1  32
#define NH2  16
#define NET  64
#define NB   16

typedef __bf16 bf8 __attribute__((ext_vector_type(8)));
typedef __bf16 bf4 __attribute__((ext_vector_type(4)));
typedef float  f4  __attribute__((ext_vector_type(4)));

#define AS3 __attribute__((address_space(3)))
#define AS1 __attribute__((address_space(1)))

__device__ __forceinline__ void gll16(const void* g, void* l) {
    __builtin_amdgcn_global_load_lds((const AS1 unsigned int*)g,
                                     (AS3 unsigned int*)l, 16, 0, 0);
}

__device__ __forceinline__ bf8 bf8_zero() {
    bf8 z;
#pragma unroll
    for (int i = 0; i < 8; i++) z[i] = (__bf16)0.0f;
    return z;
}
__device__ __forceinline__ float blo(unsigned v) { return __uint_as_float(v << 16); }
__device__ __forceinline__ float bhi(unsigned v) { return __uint_as_float(v & 0xffff0000u); }

// ---------------- prep (embT/W1T/W2T) + hist, grid-split ----------------
__global__ __launch_bounds__(256) void k_prep_hist(const float* __restrict__ embed,
                                                   const float* __restrict__ basis1,
                                                   const float* __restrict__ att1,
                                                   const float* __restrict__ basis2,
                                                   const float* __restrict__ att2,
                                                   const int* __restrict__ ei,
                                                   __bf16* __restrict__ embT,
                                                   __bf16* __restrict__ W1T,
                                                   __bf16* __restrict__ W2T,
                                                   int* __restrict__ deg) {
    int b = blockIdx.x;
    if (b < 512) {
        int idx = b * 256 + threadIdx.x;        // embT[n][k] = embed[k][n]
        int n = idx >> 11, k = idx & 2047;
        embT[idx] = (__bf16)embed[k * NEMB + n];
    } else if (b < 576) {
        int r = b - 512;
        __shared__ float a[NB];
        if (threadIdx.x < NB) a[threadIdx.x] = att1[r * NB + threadIdx.x];
        __syncthreads();
        for (int idx = threadIdx.x; idx < NH1 * NEMB; idx += 256) {
            int o = idx >> 6, i = idx & 63;
            float acc = 0.f;
#pragma unroll
            for (int bb = 0; bb < NB; bb++) acc += a[bb] * basis1[(bb * NEMB + i) * NH1 + o];
            W1T[r * (NH1 * NEMB) + idx] = (__bf16)acc;
        }
    } else if (b < 640) {
        int r = b - 576;
        __shared__ float a[NB];
        if (threadIdx.x < NB) a[threadIdx.x] = att2[r * NB + threadIdx.x];
        __syncthreads();
        for (int idx = threadIdx.x; idx < NH2 * NH1; idx += 256) {
            int o = idx >> 5, i = idx & 31;
            float acc = 0.f;
#pragma unroll
            for (int bb = 0; bb < NB; bb++) acc += a[bb] * basis2[(bb * NH1 + i) * NH2 + o];
            W2T[r * (NH2 * NH1) + idx] = (__bf16)acc;
        }
    } else {
        for (int e = (b - 640) * 256 + threadIdx.x; e < EE; e += 512 * 256)
            atomicAdd(&deg[ei[EE + e]], 1);
    }
}

// ---------------- standalone scan: 1024 threads, values in regs ----------------
__global__ __launch_bounds__(1024) void k_scan(const int* __restrict__ deg,
                                               int* __restrict__ rs,
                                               int* __restrict__ cur) {
    const int PER = 30;                        // 1024*30 = 30720 >= NN
    int t = threadIdx.x;
    int lane = t & 63, wv = t >> 6;
    int i0 = t * PER;
    int v[PER];
    int s = 0;
#pragma unroll
    for (int j = 0; j < PER; j++) {
        int i = i0 + j;
        v[j] = (i < NN) ? deg[i] : 0;
        s += v[j];
    }
    int incl = s;
#pragma unroll
    for (int off = 1; off < 64; off <<= 1) {
        int u = __shfl_up(incl, off);
        if (lane >= off) incl += u;
    }
    __shared__ int wsum[16], wbase[16];
    if (lane == 63) wsum[wv] = incl;
    __syncthreads();
    if (t == 0) {
        int acc = 0;
#pragma unroll
        for (int w = 0; w < 16; w++) { wbase[w] = acc; acc += wsum[w]; }
    }
    __syncthreads();
    int run = wbase[wv] + incl - s;
#pragma unroll
    for (int j = 0; j < PER; j++) {
        int i = i0 + j;
        if (i < NN) { rs[i] = run; cur[i] = run; run += v[j]; }
    }
    if (t == 0) rs[NN] = EE;
}

// ---------------- embed GEMM: dbuf gll staging + counted vmcnt ----------------
// 32 rows x 64 cols per block, K in 16 chunks of 128 floats.
// A: f32 x -> LDS [2][32][512B]; B: embT bf16 -> LDS [2][64][256B].
// 64KB LDS -> 2 blocks/CU; pipelining is INTRA-block via vmcnt(8) (never 0
// in-loop), raw s_barrier (no compiler drain), sched_barrier fence.
__global__ __launch_bounds__(256) void k_gemm(const float* __restrict__ x,
                                              const float* __restrict__ xnorm,
                                              const __bf16* __restrict__ embT,
                                              __bf16* __restrict__ h0b) {
    __shared__ __align__(16) float  As[2][32 * 128];    // 2 x 16,384 B
    __shared__ __align__(16) __bf16 Bs[2][64 * 128];    // 2 x 16,384 B
    int t = threadIdx.x;
    int wv = t >> 6, lane = t & 63;
    int l15 = lane & 15, kg = lane >> 4;
    int rowbase = blockIdx.x * 32;
    int half = lane >> 5;                 // A: row within 512B pair
    int bslot = lane & 31;                // A: 16B slot within 512B row
    int q16 = lane >> 4;                  // B: row within 1KB quad
    int slot16 = lane & 15;               // B: 16B slot within 256B row
    int n = wv * 16 + l15;
    int nswz = (n & 7) << 4;
    int aswz = (l15 & 7) << 4;
    f4 acc0 = (f4)0.0f, acc1 = (f4)0.0f;

    auto STAGE = [&](int c, int buf) {
#pragma unroll
        for (int i = 0; i < 4; i++) {               // A: 4 gll
            int rp = wv * 4 + i;
            int row = rp * 2 + half;
            int grow = rowbase + row;
            if (grow >= NN) grow = NN - 1;
            const char* g = (const char*)x + (size_t)grow * (IND * 4) + c * 512
                          + ((bslot * 16) ^ ((row & 7) << 4));
            gll16(g, (char*)&As[buf][0] + rp * 1024);
        }
#pragma unroll
        for (int i = 0; i < 4; i++) {               // B: 4 gll
            int rp = wv * 4 + i;
            int row = rp * 4 + q16;
            const char* g = (const char*)embT + (size_t)row * (IND * 2) + c * 256
                          + ((slot16 * 16) ^ ((row & 7) << 4));
            gll16(g, (char*)&Bs[buf][0] + rp * 1024);
        }
    };

    STAGE(0, 0);
    for (int c = 0; c < 16; c++) {
        int buf = c & 1;
        if (c < 15) {
            STAGE(c + 1, buf ^ 1);
            asm volatile("s_waitcnt vmcnt(8)" ::: "memory");   // chunk c landed
        } else {
            asm volatile("s_waitcnt vmcnt(0)" ::: "memory");
        }
        __builtin_amdgcn_s_barrier();
        __builtin_amdgcn_sched_barrier(0);
        const char* bsrow  = (const char*)&Bs[buf][0] + n * 256;
        const char* asrow0 = (const char*)&As[buf][0] + l15 * 512;
        const char* asrow1 = (const char*)&As[buf][0] + (l15 + 16) * 512;
#pragma unroll
        for (int kk = 0; kk < 4; kk++) {
            int aoff = ((kk * 128 + kg * 32) ^ aswz);
            float4 lo0 = *(const float4*)(asrow0 + aoff);
            float4 hi0 = *(const float4*)(asrow0 + (aoff ^ 16));
            float4 lo1 = *(const float4*)(asrow1 + aoff);
            float4 hi1 = *(const float4*)(asrow1 + (aoff ^ 16));
            bf8 b = *(const bf8*)(bsrow + ((kk * 64 + kg * 16) ^ nswz));
            bf8 a0, a1;
            a0[0]=(__bf16)lo0.x; a0[1]=(__bf16)lo0.y; a0[2]=(__bf16)lo0.z; a0[3]=(__bf16)lo0.w;
            a0[4]=(__bf16)hi0.x; a0[5]=(__bf16)hi0.y; a0[6]=(__bf16)hi0.z; a0[7]=(__bf16)hi0.w;
            a1[0]=(__bf16)lo1.x; a1[1]=(__bf16)lo1.y; a1[2]=(__bf16)lo1.z; a1[3]=(__bf16)lo1.w;
            a1[4]=(__bf16)hi1.x; a1[5]=(__bf16)hi1.y; a1[6]=(__bf16)hi1.z; a1[7]=(__bf16)hi1.w;
            acc0 = __builtin_amdgcn_mfma_f32_16x16x32_bf16(a0, b, acc0, 0, 0, 0);
            acc1 = __builtin_amdgcn_mfma_f32_16x16x32_bf16(a1, b, acc1, 0, 0, 0);
        }
        __builtin_amdgcn_sched_barrier(0);
        __builtin_amdgcn_s_barrier();
    }
#pragma unroll
    for (int j = 0; j < 4; j++) {
        int r0 = rowbase + kg * 4 + j;
        int r1 = r0 + 16;
        if (r0 < NN) h0b[(size_t)r0 * NEMB + n] = (__bf16)(acc0[j] / xnorm[r0]);
        if (r1 < NN) h0b[(size_t)r1 * NEMB + n] = (__bf16)(acc1[j] / xnorm[r1]);
    }
}

// ---------------- edge layer 1: hoisted loads, MFMA batch, slot store ----------------
__global__ __launch_bounds__(256) void k_edge1(const int* __restrict__ ei,
                                               const int* __restrict__ et,
                                               const __bf16* __restrict__ h0b,
                                               const __bf16* __restrict__ W1T,
                                               int* __restrict__ cur,
                                               int* __restrict__ epos,
                                               __bf16* __restrict__ msg1) {
    __shared__ __bf16 lt[4][16][32];
    int wave = threadIdx.x >> 6, lane = threadIdx.x & 63;
    int l15 = lane & 15, kg = lane >> 4;
    int wid = blockIdx.x * 4 + wave;             // 30000 waves, 32 edges each
    int row = lane >> 2, q = lane & 3;
    // ---- hoisted inputs for BOTH batches (independent loads) ----
    int er0 = wid * 32 + l15, er1 = er0 + 16;
    int et0v = et[er0],  et1v = et[er1];
    int src0 = ei[er0],  src1 = ei[er1];
    const __bf16* hp0 = h0b + (size_t)src0 * NEMB + kg * 8;
    const __bf16* hp1 = h0b + (size_t)src1 * NEMB + kg * 8;
    bf8 a00 = *(const bf8*)hp0;
    bf8 a01 = *(const bf8*)(hp0 + 32);
    bf8 a10 = *(const bf8*)hp1;
    bf8 a11 = *(const bf8*)(hp1 + 32);
    int slot0 = 0, slot1 = 0;
    if (kg == 0) {
        slot0 = atomicAdd(&cur[ei[EE + er0]], 1);
        epos[er0] = slot0;
        slot1 = atomicAdd(&cur[ei[EE + er1]], 1);
        epos[er1] = slot1;
    }
    bf8 zero = bf8_zero();
#pragma unroll
    for (int b = 0; b < 2; b++) {
        int my_et = b ? et1v : et0v;
        bf8 a0 = b ? a10 : a00;
        bf8 a1 = b ? a11 : a01;
        int slotv = b ? slot1 : slot0;
        f4 c0 = (f4)0.0f, c1 = (f4)0.0f;
        int pos = 0;
        while (pos < 16) {
            int r = __shfl(my_et, pos);
            unsigned long long bl = __ballot(my_et == r);
            unsigned m16 = (unsigned)(bl & 0xFFFFull);
            int run = __builtin_ctz(~(m16 >> pos));
            int end = pos + run;
            const __bf16* wb = W1T + (size_t)r * (NH1 * NEMB) + (size_t)l15 * NEMB + kg * 8;
            bf8 b00 = *(const bf8*)(wb);
            bf8 b01 = *(const bf8*)(wb + 32);
            bf8 b10 = *(const bf8*)(wb + 16 * NEMB);
            bf8 b11 = *(const bf8*)(wb + 16 * NEMB + 32);
            bool use = (l15 >= pos) && (l15 < end);
            bf8 ua0 = use ? a0 : zero;
            bf8 ua1 = use ? a1 : zero;
            c0 = __builtin_amdgcn_mfma_f32_16x16x32_bf16(ua0, b00, c0, 0, 0, 0);
            c0 = __builtin_amdgcn_mfma_f32_16x16x32_bf16(ua1, b01, c0, 0, 0, 0);
            c1 = __builtin_amdgcn_mfma_f32_16x16x32_bf16(ua0, b10, c1, 0, 0, 0);
            c1 = __builtin_amdgcn_mfma_f32_16x16x32_bf16(ua1, b11, c1, 0, 0, 0);
            pos = end;
        }
#pragma unroll
        for (int j = 0; j < 4; j++) {
            lt[wave][kg * 4 + j][l15]      = (__bf16)c0[j];
            lt[wave][kg * 4 + j][16 + l15] = (__bf16)c1[j];
        }
        int slot = __shfl(slotv, row);
        bf8 v = *(const bf8*)&lt[wave][row][q * 8];
        *(bf8*)(msg1 + (size_t)slot * NH1 + q * 8) = v;
    }
}

// ---------------- edge layer 2 ----------------
__global__ __launch_bounds__(256) void k_edge2(const int* __restrict__ ei,
                                               const int* __restrict__ et,
                                               const int* __restrict__ epos,
                                               const __bf16* __restrict__ h1b,
                                               const __bf16* __restrict__ W2T,
                                               __bf16* __restrict__ msg2) {
    __shared__ __bf16 lt[4][16][16];
    int wave = threadIdx.x >> 6, lane = threadIdx.x & 63;
    int l15 = lane & 15, kg = lane >> 4;
    int wid = blockIdx.x * 4 + wave;
    int row = lane >> 2, q = lane & 3;
    int er0 = wid * 32 + l15, er1 = er0 + 16;
    int et0v = et[er0],  et1v = et[er1];
    int src0 = ei[er0],  src1 = ei[er1];
    int sl0  = epos[er0], sl1 = epos[er1];
    bf8 ab0 = *(const bf8*)(h1b + (size_t)src0 * NH1 + kg * 8);
    bf8 ab1 = *(const bf8*)(h1b + (size_t)src1 * NH1 + kg * 8);
    bf8 zero = bf8_zero();
#pragma unroll
    for (int b = 0; b < 2; b++) {
        int my_et = b ? et1v : et0v;
        bf8 a = b ? ab1 : ab0;
        int slotv = b ? sl1 : sl0;
        f4 c = (f4)0.0f;
        int pos = 0;
        while (pos < 16) {
            int r = __shfl(my_et, pos);
            unsigned long long bl = __ballot(my_et == r);
            unsigned m16 = (unsigned)(bl & 0xFFFFull);
            int run = __builtin_ctz(~(m16 >> pos));
            int end = pos + run;
            bf8 bb = *(const bf8*)(W2T + (size_t)r * (NH2 * NH1) + (size_t)l15 * NH1 + kg * 8);
            bool use = (l15 >= pos) && (l15 < end);
            c = __builtin_amdgcn_mfma_f32_16x16x32_bf16(use ? a : zero, bb, c, 0, 0, 0);
            pos = end;
        }
#pragma unroll
        for (int j = 0; j < 4; j++) lt[wave][kg * 4 + j][l15] = (__bf16)c[j];
        int slot = __shfl(slotv, row);
        bf4 v = *(const bf4*)&lt[wave][row][q * 4];
        *(bf4*)(msg2 + (size_t)slot * NH2 + q * 4) = v;
    }
}

// ---------------- per-dst aggregation (2-way unrolled stream) ----------------
__global__ __launch_bounds__(256) void k_agg1(const int* __restrict__ row_start,
                                              const unsigned* __restrict__ msg1,   // bf16x2 words
                                              const __bf16* __restrict__ h0b,
                                              const float* __restrict__ root1,
                                              const float* __restrict__ bias1,
                                              __bf16* __restrict__ h1b) {
    int dst = blockIdx.x * 4 + (threadIdx.x >> 6);
    int lane = threadIdx.x & 63;
    int c2 = lane & 15;
    int m  = lane >> 4;
    float ax = 0.f, ay = 0.f;
    bf8 hv0 = *(const bf8*)(h0b + (size_t)dst * NEMB + m * 16);
    bf8 hv1 = *(const bf8*)(h0b + (size_t)dst * NEMB + m * 16 + 8);
    const float2* rt = (const float2*)root1;
#pragma unroll
    for (int k = 0; k < 8; k++) {
        float a = (float)hv0[k];
        float2 w = rt[(size_t)(m * 16 + k) * 16 + c2];
        ax += a * w.x; ay += a * w.y;
    }
#pragma unroll
    for (int k = 0; k < 8; k++) {
        float a = (float)hv1[k];
        float2 w = rt[(size_t)(m * 16 + 8 + k) * 16 + c2];
        ax += a * w.x; ay += a * w.y;
    }
    int s = row_start[dst], e = row_start[dst + 1];
    int i = s + m;
    for (; i + 4 < e; i += 8) {
        unsigned v0 = msg1[(size_t)i * 16 + c2];
        unsigned v1 = msg1[(size_t)(i + 4) * 16 + c2];
        ax += blo(v0); ay += bhi(v0);
        ax += blo(v1); ay += bhi(v1);
    }
    if (i < e) {
        unsigned v = msg1[(size_t)i * 16 + c2];
        ax += blo(v); ay += bhi(v);
    }
    ax += __shfl_xor(ax, 16); ay += __shfl_xor(ay, 16);
    ax += __shfl_xor(ax, 32); ay += __shfl_xor(ay, 32);
    if (m == 0) {
        float2 bsv = ((const float2*)bias1)[c2];
        __bf16 o0 = (__bf16)fmaxf(ax + bsv.x, 0.f);
        __bf16 o1 = (__bf16)fmaxf(ay + bsv.y, 0.f);
        __bf16* hp = h1b + (size_t)dst * NH1 + 2 * c2;
        hp[0] = o0; hp[1] = o1;
    }
}

__global__ __launch_bounds__(256) void k_agg2(const int* __restrict__ row_start,
                                              const unsigned* __restrict__ msg2,   // bf16x2 words
                                              const __bf16* __restrict__ h1b,
                                              const float* __restrict__ root2,
                                              const float* __restrict__ bias2,
                                              float* __restrict__ out) {
    int dst = blockIdx.x * 4 + (threadIdx.x >> 6);
    int lane = threadIdx.x & 63;
    int c2 = lane & 7;
    int m  = lane >> 3;
    float ax = 0.f, ay = 0.f;
    bf4 hv = *(const bf4*)(h1b + (size_t)dst * NH1 + m * 4);
    const float2* rt = (const float2*)root2;
#pragma unroll
    for (int k = 0; k < 4; k++) {
        float a = (float)hv[k];
        float2 w = rt[(size_t)(m * 4 + k) * 8 + c2];
        ax += a * w.x; ay += a * w.y;
    }
    int s = row_start[dst], e = row_start[dst + 1];
    int i = s + m;
    for (; i + 8 < e; i += 16) {
        unsigned v0 = msg2[(size_t)i * 8 + c2];
        unsigned v1 = msg2[(size_t)(i + 8) * 8 + c2];
        ax += blo(v0); ay += bhi(v0);
        ax += blo(v1); ay += bhi(v1);
    }
    if (i < e) {
        unsigned v = msg2[(size_t)i * 8 + c2];
        ax += blo(v); ay += bhi(v);
    }
    ax += __shfl_xor(ax, 8);  ay += __shfl_xor(ay, 8);
    ax += __shfl_xor(ax, 16); ay += __shfl_xor(ay, 16);
    ax += __shfl_xor(ax, 32); ay += __shfl_xor(ay, 32);
    if (m == 0) {
        float2 bsv = ((const float2*)bias2)[c2];
        float2 o;
        o.x = fmaxf(ax + bsv.x, 0.f);
        o.y = fmaxf(ay + bsv.y, 0.f);
        ((float2*)out)[(size_t)dst * 8 + c2] = o;
    }
}

// ---------------- launch ----------------
extern "C" void kernel_launch(void* const* d_in, const int* in_sizes, int n_in,
                              void* d_out, int out_size, void* d_ws, size_t ws_size,
                              hipStream_t stream) {
    const float* x      = (const float*)d_in[0];
    const int*   ei     = (const int*)d_in[1];
    const int*   et     = (const int*)d_in[2];
    const float* xnorm  = (const float*)d_in[4];
    const float* embed  = (const float*)d_in[5];
    const float* basis1 = (const float*)d_in[6];
    const float* att1   = (const float*)d_in[7];
    const float* root1  = (const float*)d_in[8];
    const float* bias1  = (const float*)d_in[9];
    const float* basis2 = (const float*)d_in[10];
    const float* att2   = (const float*)d_in[11];
    const float* root2  = (const float*)d_in[12];
    const float* bias2  = (const float*)d_in[13];
    float* out = (float*)d_out;

    char* ws = (char*)d_ws;
    __bf16* embT = (__bf16*)(ws + 0);              //   262,144
    __bf16* W1T  = (__bf16*)(ws + 262144);         //   262,144
    __bf16* W2T  = (__bf16*)(ws + 524288);         //    65,536
    __bf16* h0b  = (__bf16*)(ws + 589824);         // 3,840,000
    __bf16* h1b  = (__bf16*)(ws + 4429824);        // 1,920,000
    int*    deg  = (int*)   (ws + 6349824);        //   120,000
    int*    rs   = (int*)   (ws + 6469824);        //   120,064
    int*    cur  = (int*)   (ws + 6589888);        //   120,000
    int*    epos = (int*)   (ws + 6709888);        // 3,840,000
    __bf16* msg1 = (__bf16*)(ws + 10549888);       // 61,440,000
    __bf16* msg2 = (__bf16*)(ws + 71989888);       // 30,720,000  (end ~102.7 MB)

    hipMemsetAsync(deg, 0, NN * sizeof(int), stream);
    k_prep_hist<<<1152, 256,  0, stream>>>(embed, basis1, att1, basis2, att2, ei,
                                           embT, W1T, W2T, deg);
    k_scan     <<<1,    1024, 0, stream>>>(deg, rs, cur);
    k_gemm     <<<938,  256,  0, stream>>>(x, xnorm, embT, h0b);
    k_edge1    <<<7500, 256,  0, stream>>>(ei, et, h0b, W1T, cur, epos, msg1);
    k_agg1     <<<7500, 256,  0, stream>>>(rs, (const unsigned*)msg1, h0b, root1, bias1, h1b);
    k_edge2    <<<7500, 256,  0, stream>>>(ei, et, epos, h1b, W2T, msg2);
    k_agg2     <<<7500, 256,  0, stream>>>(rs, (const unsigned*)msg2, h1b, root2, bias2, out);
}

// Round 10
// 255.138 us; speedup vs baseline: 1.7372x; 1.1330x over previous
//
#include <hip/hip_runtime.h>
#include <hip/hip_bf16.h>

#define NN   30000
#define EE   960000
#define IND  2048
#define NEMB 64
#define NH1  32
#define NH2  16
#define NET  64
#define NB   16

typedef __bf16 bf8 __attribute__((ext_vector_type(8)));
typedef __bf16 bf4 __attribute__((ext_vector_type(4)));
typedef __bf16 bf2 __attribute__((ext_vector_type(2)));
typedef float  f4  __attribute__((ext_vector_type(4)));

#define AS3 __attribute__((address_space(3)))
#define AS1 __attribute__((address_space(1)))

__device__ __forceinline__ void gll16(const void* g, void* l) {
    __builtin_amdgcn_global_load_lds((const AS1 unsigned int*)g,
                                     (AS3 unsigned int*)l, 16, 0, 0);
}

__device__ __forceinline__ bf8 bf8_zero() {
    bf8 z;
#pragma unroll
    for (int i = 0; i < 8; i++) z[i] = (__bf16)0.0f;
    return z;
}

// ---------------- prep: embT + W1T + W2T (grid-split) ----------------
__global__ __launch_bounds__(256) void k_prep(const float* __restrict__ embed,
                                              const float* __restrict__ basis1,
                                              const float* __restrict__ att1,
                                              const float* __restrict__ basis2,
                                              const float* __restrict__ att2,
                                              __bf16* __restrict__ embT,
                                              __bf16* __restrict__ W1T,
                                              __bf16* __restrict__ W2T) {
    int b = blockIdx.x;
    if (b < 512) {
        int idx = b * 256 + threadIdx.x;        // embT[n][k] = embed[k][n]
        int n = idx >> 11, k = idx & 2047;
        embT[idx] = (__bf16)embed[k * NEMB + n];
    } else if (b < 576) {
        int r = b - 512;
        __shared__ float a[NB];
        if (threadIdx.x < NB) a[threadIdx.x] = att1[r * NB + threadIdx.x];
        __syncthreads();
        for (int idx = threadIdx.x; idx < NH1 * NEMB; idx += 256) {
            int o = idx >> 6, i = idx & 63;
            float acc = 0.f;
#pragma unroll
            for (int bb = 0; bb < NB; bb++) acc += a[bb] * basis1[(bb * NEMB + i) * NH1 + o];
            W1T[r * (NH1 * NEMB) + idx] = (__bf16)acc;
        }
    } else {
        int r = b - 576;
        __shared__ float a[NB];
        if (threadIdx.x < NB) a[threadIdx.x] = att2[r * NB + threadIdx.x];
        __syncthreads();
        for (int idx = threadIdx.x; idx < NH2 * NH1; idx += 256) {
            int o = idx >> 5, i = idx & 31;
            float acc = 0.f;
#pragma unroll
            for (int bb = 0; bb < NB; bb++) acc += a[bb] * basis2[(bb * NH1 + i) * NH2 + o];
            W2T[r * (NH2 * NH1) + idx] = (__bf16)acc;
        }
    }
}

// ---------------- embed GEMM (dbuf gll, counted vmcnt) + fused init1 ----------------
// 32 rows x 64 cols per block, K in 16 chunks of 128 floats.
// Epilogue: h0 tile -> LDS -> out1 = bias1 + h0 @ root1 (fp32), saving a
// separate init kernel + a full re-read of h0b.
__global__ __launch_bounds__(256) void k_gemm(const float* __restrict__ x,
                                              const float* __restrict__ xnorm,
                                              const __bf16* __restrict__ embT,
                                              const float* __restrict__ root1,
                                              const float* __restrict__ bias1,
                                              __bf16* __restrict__ h0b,
                                              float* __restrict__ out1) {
    __shared__ __align__(16) float  As[2][32 * 128];    // 2 x 16,384 B
    __shared__ __align__(16) __bf16 Bs[2][64 * 128];    // 2 x 16,384 B
    int t = threadIdx.x;
    int wv = t >> 6, lane = t & 63;
    int l15 = lane & 15, kg = lane >> 4;
    int rowbase = blockIdx.x * 32;
    int half = lane >> 5;
    int bslot = lane & 31;
    int q16 = lane >> 4;
    int slot16 = lane & 15;
    int n = wv * 16 + l15;
    int nswz = (n & 7) << 4;
    int aswz = (l15 & 7) << 4;
    f4 acc0 = (f4)0.0f, acc1 = (f4)0.0f;

    auto STAGE = [&](int c, int buf) {
#pragma unroll
        for (int i = 0; i < 4; i++) {               // A: 4 gll
            int rp = wv * 4 + i;
            int row = rp * 2 + half;
            int grow = rowbase + row;
            if (grow >= NN) grow = NN - 1;
            const char* g = (const char*)x + (size_t)grow * (IND * 4) + c * 512
                          + ((bslot * 16) ^ ((row & 7) << 4));
            gll16(g, (char*)&As[buf][0] + rp * 1024);
        }
#pragma unroll
        for (int i = 0; i < 4; i++) {               // B: 4 gll
            int rp = wv * 4 + i;
            int row = rp * 4 + q16;
            const char* g = (const char*)embT + (size_t)row * (IND * 2) + c * 256
                          + ((slot16 * 16) ^ ((row & 7) << 4));
            gll16(g, (char*)&Bs[buf][0] + rp * 1024);
        }
    };

    STAGE(0, 0);
    for (int c = 0; c < 16; c++) {
        int buf = c & 1;
        if (c < 15) {
            STAGE(c + 1, buf ^ 1);
            asm volatile("s_waitcnt vmcnt(8)" ::: "memory");
        } else {
            asm volatile("s_waitcnt vmcnt(0)" ::: "memory");
        }
        __builtin_amdgcn_s_barrier();
        __builtin_amdgcn_sched_barrier(0);
        const char* bsrow  = (const char*)&Bs[buf][0] + n * 256;
        const char* asrow0 = (const char*)&As[buf][0] + l15 * 512;
        const char* asrow1 = (const char*)&As[buf][0] + (l15 + 16) * 512;
#pragma unroll
        for (int kk = 0; kk < 4; kk++) {
            int aoff = ((kk * 128 + kg * 32) ^ aswz);
            float4 lo0 = *(const float4*)(asrow0 + aoff);
            float4 hi0 = *(const float4*)(asrow0 + (aoff ^ 16));
            float4 lo1 = *(const float4*)(asrow1 + aoff);
            float4 hi1 = *(const float4*)(asrow1 + (aoff ^ 16));
            bf8 b = *(const bf8*)(bsrow + ((kk * 64 + kg * 16) ^ nswz));
            bf8 a0, a1;
            a0[0]=(__bf16)lo0.x; a0[1]=(__bf16)lo0.y; a0[2]=(__bf16)lo0.z; a0[3]=(__bf16)lo0.w;
            a0[4]=(__bf16)hi0.x; a0[5]=(__bf16)hi0.y; a0[6]=(__bf16)hi0.z; a0[7]=(__bf16)hi0.w;
            a1[0]=(__bf16)lo1.x; a1[1]=(__bf16)lo1.y; a1[2]=(__bf16)lo1.z; a1[3]=(__bf16)lo1.w;
            a1[4]=(__bf16)hi1.x; a1[5]=(__bf16)hi1.y; a1[6]=(__bf16)hi1.z; a1[7]=(__bf16)hi1.w;
            acc0 = __builtin_amdgcn_mfma_f32_16x16x32_bf16(a0, b, acc0, 0, 0, 0);
            acc1 = __builtin_amdgcn_mfma_f32_16x16x32_bf16(a1, b, acc1, 0, 0, 0);
        }
        __builtin_amdgcn_sched_barrier(0);
        __builtin_amdgcn_s_barrier();
    }
    // ---- epilogue: store h0 (global + LDS), then fused init1 ----
    __bf16* h0s = (__bf16*)&As[0][0];          // 32 x 64 bf16 = 4 KB
#pragma unroll
    for (int j = 0; j < 4; j++) {
        int lr0 = kg * 4 + j, lr1 = lr0 + 16;
        int r0 = rowbase + lr0, r1 = rowbase + lr1;
        float v0 = 0.f, v1 = 0.f;
        if (r0 < NN) v0 = acc0[j] / xnorm[r0];
        if (r1 < NN) v1 = acc1[j] / xnorm[r1];
        __bf16 b0 = (__bf16)v0, b1 = (__bf16)v1;
        if (r0 < NN) h0b[(size_t)r0 * NEMB + n] = b0;
        if (r1 < NN) h0b[(size_t)r1 * NEMB + n] = b1;
        h0s[lr0 * NEMB + n] = b0;
        h0s[lr1 * NEMB + n] = b1;
    }
    __syncthreads();
    // init1: out1[row][col] = bias1[col] + sum_k h0[row][k]*root1[k][col]
    // thread t: row = t>>3, cols = (t&7)*4 .. +3
    {
        int row = t >> 3, c0 = (t & 7) * 4;
        int grow = rowbase + row;
        if (grow < NN) {
            const __bf16* hr = h0s + row * NEMB;
            float4 acc = *(const float4*)(bias1 + c0);
#pragma unroll
            for (int k = 0; k < NEMB; k++) {
                float a = (float)hr[k];
                float4 w = *(const float4*)(root1 + k * NH1 + c0);
                acc.x += a * w.x; acc.y += a * w.y;
                acc.z += a * w.z; acc.w += a * w.w;
            }
            *(float4*)(out1 + (size_t)grow * NH1 + c0) = acc;
        }
    }
}

// ---------------- edge layer 1: hoisted loads, MFMA batch, atomic scatter ----------------
__global__ __launch_bounds__(256) void k_edge1(const int* __restrict__ ei,
                                               const int* __restrict__ et,
                                               const __bf16* __restrict__ h0b,
                                               const __bf16* __restrict__ W1T,
                                               float* __restrict__ out1) {
    int wave = threadIdx.x >> 6, lane = threadIdx.x & 63;
    int l15 = lane & 15, kg = lane >> 4;
    int wid = blockIdx.x * 4 + wave;             // 30000 waves, 32 edges each
    int er0 = wid * 32 + l15, er1 = er0 + 16;
    int et0v = et[er0],  et1v = et[er1];
    int src0 = ei[er0],  src1 = ei[er1];
    int dst0 = ei[EE + er0], dst1 = ei[EE + er1];
    const __bf16* hp0 = h0b + (size_t)src0 * NEMB + kg * 8;
    const __bf16* hp1 = h0b + (size_t)src1 * NEMB + kg * 8;
    bf8 a00 = *(const bf8*)hp0;
    bf8 a01 = *(const bf8*)(hp0 + 32);
    bf8 a10 = *(const bf8*)hp1;
    bf8 a11 = *(const bf8*)(hp1 + 32);
    bf8 zero = bf8_zero();
#pragma unroll
    for (int b = 0; b < 2; b++) {
        int my_et = b ? et1v : et0v;
        int my_dst = b ? dst1 : dst0;
        bf8 a0 = b ? a10 : a00;
        bf8 a1 = b ? a11 : a01;
        f4 c0 = (f4)0.0f, c1 = (f4)0.0f;
        int pos = 0;
        while (pos < 16) {
            int r = __shfl(my_et, pos);
            unsigned long long bl = __ballot(my_et == r);
            unsigned m16 = (unsigned)(bl & 0xFFFFull);
            int run = __builtin_ctz(~(m16 >> pos));
            int end = pos + run;
            const __bf16* wb = W1T + (size_t)r * (NH1 * NEMB) + (size_t)l15 * NEMB + kg * 8;
            bf8 b00 = *(const bf8*)(wb);
            bf8 b01 = *(const bf8*)(wb + 32);
            bf8 b10 = *(const bf8*)(wb + 16 * NEMB);
            bf8 b11 = *(const bf8*)(wb + 16 * NEMB + 32);
            bool use = (l15 >= pos) && (l15 < end);
            bf8 ua0 = use ? a0 : zero;
            bf8 ua1 = use ? a1 : zero;
            c0 = __builtin_amdgcn_mfma_f32_16x16x32_bf16(ua0, b00, c0, 0, 0, 0);
            c0 = __builtin_amdgcn_mfma_f32_16x16x32_bf16(ua1, b01, c0, 0, 0, 0);
            c1 = __builtin_amdgcn_mfma_f32_16x16x32_bf16(ua0, b10, c1, 0, 0, 0);
            c1 = __builtin_amdgcn_mfma_f32_16x16x32_bf16(ua1, b11, c1, 0, 0, 0);
            pos = end;
        }
#pragma unroll
        for (int j = 0; j < 4; j++) {
            int eidx = kg * 4 + j;               // C row = edge index in batch
            int dst = __shfl(my_dst, eidx);
            atomicAdd(out1 + (size_t)dst * NH1 + l15,      c0[j]);
            atomicAdd(out1 + (size_t)dst * NH1 + 16 + l15, c1[j]);
        }
    }
}

// ---------------- mid: relu(out1) -> h1b bf16 AND out = bias2 + h1 @ root2 ----------------
__global__ __launch_bounds__(256) void k_mid(const float* __restrict__ out1,
                                             const float* __restrict__ root2,
                                             const float* __restrict__ bias2,
                                             __bf16* __restrict__ h1b,
                                             float* __restrict__ out) {
    int t = threadIdx.x;
    int row = blockIdx.x * 16 + (t >> 4);        // 1875 blocks exact
    int col = t & 15;
    const float* orow = out1 + (size_t)row * NH1;
    float h[NH1];
#pragma unroll
    for (int k = 0; k < NH1; k++) h[k] = fmaxf(orow[k], 0.f);
    bf2 hb;
    hb[0] = (__bf16)h[2 * col];
    hb[1] = (__bf16)h[2 * col + 1];
    *(bf2*)(h1b + (size_t)row * NH1 + 2 * col) = hb;
    float acc = bias2[col];
#pragma unroll
    for (int k = 0; k < NH1; k++) acc += h[k] * root2[k * NH2 + col];
    out[(size_t)row * NH2 + col] = acc;
}

// ---------------- edge layer 2: atomic scatter ----------------
__global__ __launch_bounds__(256) void k_edge2(const int* __restrict__ ei,
                                               const int* __restrict__ et,
                                               const __bf16* __restrict__ h1b,
                                               const __bf16* __restrict__ W2T,
                                               float* __restrict__ out) {
    int wave = threadIdx.x >> 6, lane = threadIdx.x & 63;
    int l15 = lane & 15, kg = lane >> 4;
    int wid = blockIdx.x * 4 + wave;
    int er0 = wid * 32 + l15, er1 = er0 + 16;
    int et0v = et[er0],  et1v = et[er1];
    int src0 = ei[er0],  src1 = ei[er1];
    int dst0 = ei[EE + er0], dst1 = ei[EE + er1];
    bf8 ab0 = *(const bf8*)(h1b + (size_t)src0 * NH1 + kg * 8);
    bf8 ab1 = *(const bf8*)(h1b + (size_t)src1 * NH1 + kg * 8);
    bf8 zero = bf8_zero();
#pragma unroll
    for (int b = 0; b < 2; b++) {
        int my_et = b ? et1v : et0v;
        int my_dst = b ? dst1 : dst0;
        bf8 a = b ? ab1 : ab0;
        f4 c = (f4)0.0f;
        int pos = 0;
        while (pos < 16) {
            int r = __shfl(my_et, pos);
            unsigned long long bl = __ballot(my_et == r);
            unsigned m16 = (unsigned)(bl & 0xFFFFull);
            int run = __builtin_ctz(~(m16 >> pos));
            int end = pos + run;
            bf8 bb = *(const bf8*)(W2T + (size_t)r * (NH2 * NH1) + (size_t)l15 * NH1 + kg * 8);
            bool use = (l15 >= pos) && (l15 < end);
            c = __builtin_amdgcn_mfma_f32_16x16x32_bf16(use ? a : zero, bb, c, 0, 0, 0);
            pos = end;
        }
#pragma unroll
        for (int j = 0; j < 4; j++) {
            int eidx = kg * 4 + j;
            int dst = __shfl(my_dst, eidx);
            atomicAdd(out + (size_t)dst * NH2 + l15, c[j]);
        }
    }
}

// ---------------- relu2 (in place on d_out) ----------------
__global__ __launch_bounds__(256) void k_relu2(float* __restrict__ o) {
    int i = blockIdx.x * 256 + threadIdx.x;
    if (i >= NN * NH2 / 4) return;
    float4 v = ((float4*)o)[i];
    v.x = fmaxf(v.x, 0.f); v.y = fmaxf(v.y, 0.f);
    v.z = fmaxf(v.z, 0.f); v.w = fmaxf(v.w, 0.f);
    ((float4*)o)[i] = v;
}

// ---------------- launch ----------------
extern "C" void kernel_launch(void* const* d_in, const int* in_sizes, int n_in,
                              void* d_out, int out_size, void* d_ws, size_t ws_size,
                              hipStream_t stream) {
    const float* x      = (const float*)d_in[0];
    const int*   ei     = (const int*)d_in[1];
    const int*   et     = (const int*)d_in[2];
    const float* xnorm  = (const float*)d_in[4];
    const float* embed  = (const float*)d_in[5];
    const float* basis1 = (const float*)d_in[6];
    const float* att1   = (const float*)d_in[7];
    const float* root1  = (const float*)d_in[8];
    const float* bias1  = (const float*)d_in[9];
    const float* basis2 = (const float*)d_in[10];
    const float* att2   = (const float*)d_in[11];
    const float* root2  = (const float*)d_in[12];
    const float* bias2  = (const float*)d_in[13];
    float* out = (float*)d_out;

    char* ws = (char*)d_ws;
    __bf16* embT = (__bf16*)(ws + 0);              //   262,144
    __bf16* W1T  = (__bf16*)(ws + 262144);         //   262,144
    __bf16* W2T  = (__bf16*)(ws + 524288);         //    65,536
    __bf16* h0b  = (__bf16*)(ws + 589824);         // 3,840,000
    float*  out1 = (float*) (ws + 4429824);        // 3,840,000
    __bf16* h1b  = (__bf16*)(ws + 8269824);        // 1,920,000  (end ~10.2 MB)

    k_prep <<<640,  256, 0, stream>>>(embed, basis1, att1, basis2, att2, embT, W1T, W2T);
    k_gemm <<<938,  256, 0, stream>>>(x, xnorm, embT, root1, bias1, h0b, out1);
    k_edge1<<<7500, 256, 0, stream>>>(ei, et, h0b, W1T, out1);
    k_mid  <<<1875, 256, 0, stream>>>(out1, root2, bias2, h1b, out);
    k_edge2<<<7500, 256, 0, stream>>>(ei, et, h1b, W2T, out);
    k_relu2<<<469,  256, 0, stream>>>(out);
}